// Round 5
// baseline (993.355 us; speedup 1.0000x reference)
//
#include <hip/hip_runtime.h>

#define HID 128

typedef __attribute__((ext_vector_type(8))) short short8;
typedef __attribute__((ext_vector_type(4))) float f32x4;

__device__ __forceinline__ float bf2f(unsigned short u) {
    unsigned int x = ((unsigned int)u) << 16;
    return __builtin_bit_cast(float, x);
}
__device__ __forceinline__ unsigned short f2bf(float f) {
    unsigned int u = __builtin_bit_cast(unsigned int, f);
    u += 0x7fffu + ((u >> 16) & 1u);
    return (unsigned short)(u >> 16);
}

// ---------------- weight prep: fp32 [K,N] (optionally two stacked sources) ->
// fragment layout hi/lo: elem (k,n) at ((k/32)*N + n)*32 + k%32 ----------------
__global__ __launch_bounds__(256) void k_prepw(const float* __restrict__ s1, int k1,
    const float* __restrict__ s2, int k2, int Kp, int N,
    unsigned short* __restrict__ whi, unsigned short* __restrict__ wlo)
{
    int i = blockIdx.x * 256 + threadIdx.x;
    if (i >= Kp * N) return;
    int k = i / N, nn = i - k * N;
    float v = 0.f;
    if (k < k1) v = s1[(size_t)k * N + nn];
    else if (k < k1 + k2) v = s2[(size_t)(k - k1) * N + nn];
    unsigned short h = f2bf(v);
    unsigned short l = f2bf(v - bf2f(h));
    size_t o = ((size_t)(k >> 5) * N + nn) * 32 + (k & 31);
    whi[o] = h; wlo[o] = l;
}

// ---------------- input feature prestack: [xnum | emb0..3 | pad] -> bf16 hi/lo pairs,
// A0 row-major [n][192] = [hi(96) | lo(96)].  6 chunks of 16 cols per row. ----------------
__global__ __launch_bounds__(256) void k_stack0(
    const float* __restrict__ xnum, const int* __restrict__ xcat,
    const float* __restrict__ e0, const float* __restrict__ e1,
    const float* __restrict__ e2, const float* __restrict__ e3,
    unsigned short* __restrict__ A0, int n)
{
    int g = blockIdx.x * 256 + threadIdx.x;
    int r = g / 6, c = g - r * 6;              // 6 chunks of 16 cols (96 features)
    if (r >= n) return;
    int4 cc = ((const int4*)xcat)[r];
    float v[16];
    int base = c * 16;
    #pragma unroll
    for (int j = 0; j < 16; ++j) {
        int col = base + j;
        float val;
        if      (col < 32) val = xnum[(size_t)r * 32 + col];
        else if (col < 42) val = e0[(size_t)cc.x * 10 + (col - 32)];
        else if (col < 48) val = e1[(size_t)cc.y * 6  + (col - 42)];
        else if (col < 53) val = e2[(size_t)cc.z * 5  + (col - 48)];
        else if (col < 71) val = e3[(size_t)cc.w * 18 + (col - 53)];
        else               val = 0.f;
        v[j] = val;
    }
    unsigned int ph[8], pl[8];
    #pragma unroll
    for (int j = 0; j < 8; ++j) {
        unsigned short h0 = f2bf(v[2*j]),   h1 = f2bf(v[2*j+1]);
        unsigned short l0 = f2bf(v[2*j]   - bf2f(h0));
        unsigned short l1 = f2bf(v[2*j+1] - bf2f(h1));
        ph[j] = (unsigned int)h0 | ((unsigned int)h1 << 16);
        pl[j] = (unsigned int)l0 | ((unsigned int)l1 << 16);
    }
    unsigned int* dh = (unsigned int*)(A0 + (size_t)r * 192 + base);
    unsigned int* dl = (unsigned int*)(A0 + (size_t)r * 192 + 96 + base);
    uint4 a; a.x = ph[0]; a.y = ph[1]; a.z = ph[2]; a.w = ph[3];
    uint4 b; b.x = ph[4]; b.y = ph[5]; b.z = ph[6]; b.w = ph[7];
    ((uint4*)dh)[0] = a; ((uint4*)dh)[1] = b;
    a.x = pl[0]; a.y = pl[1]; a.z = pl[2]; a.w = pl[3];
    b.x = pl[4]; b.y = pl[5]; b.z = pl[6]; b.w = pl[7];
    ((uint4*)dl)[0] = a; ((uint4*)dl)[1] = b;
}

// ---------------- CSR build ----------------
__global__ __launch_bounds__(256) void k_count(const int* __restrict__ dst,
                                               int* __restrict__ cnt, int ecount)
{
    int i = blockIdx.x * blockDim.x + threadIdx.x;
    int stride = gridDim.x * blockDim.x;
    for (; i < ecount; i += stride) atomicAdd(&cnt[dst[i]], 1);
}

__global__ __launch_bounds__(1024) void k_scan1(const int* __restrict__ cnt,
    int* __restrict__ excl, int* __restrict__ bsum, int n)
{
    __shared__ int sm[1024];
    int t = threadIdx.x;
    int base = blockIdx.x * 4096 + t * 4;
    int v0 = (base + 0 < n) ? cnt[base + 0] : 0;
    int v1 = (base + 1 < n) ? cnt[base + 1] : 0;
    int v2 = (base + 2 < n) ? cnt[base + 2] : 0;
    int v3 = (base + 3 < n) ? cnt[base + 3] : 0;
    int s = v0 + v1 + v2 + v3;
    sm[t] = s;
    __syncthreads();
    for (int offd = 1; offd < 1024; offd <<= 1) {
        int tv = (t >= offd) ? sm[t - offd] : 0;
        __syncthreads();
        sm[t] += tv;
        __syncthreads();
    }
    int incl = sm[t];
    int ex = incl - s;
    if (t == 1023) bsum[blockIdx.x] = incl;
    if (base + 0 < n) excl[base + 0] = ex; ex += v0;
    if (base + 1 < n) excl[base + 1] = ex; ex += v1;
    if (base + 2 < n) excl[base + 2] = ex; ex += v2;
    if (base + 3 < n) excl[base + 3] = ex;
}

__global__ void k_scan2(int* __restrict__ bsum, int nb)
{
    if (threadIdx.x == 0 && blockIdx.x == 0) {
        int run = 0;
        for (int i = 0; i < nb; ++i) { int t = bsum[i]; bsum[i] = run; run += t; }
    }
}

__global__ __launch_bounds__(256) void k_scan3(int* __restrict__ row_ptr,
    const int* __restrict__ bsum, int* __restrict__ cursor, int n, int ecount)
{
    int i = blockIdx.x * 256 + threadIdx.x;
    if (i < n) {
        int v = row_ptr[i] + bsum[i >> 12];
        row_ptr[i] = v;
        cursor[i] = v;
    }
    if (i == 0) row_ptr[n] = ecount;
}

__global__ __launch_bounds__(256) void k_fill(const int* __restrict__ src,
    const int* __restrict__ dst, int* __restrict__ cursor,
    int* __restrict__ col, int ecount)
{
    int i = blockIdx.x * blockDim.x + threadIdx.x;
    int stride = gridDim.x * blockDim.x;
    for (; i < ecount; i += stride) {
        int d = dst[i];
        int slot = atomicAdd(&cursor[d], 1);
        col[slot] = src[i];
    }
}

// ---------------- mean aggregation over bf16 pairs: one wave per node ----------------
__global__ __launch_bounds__(256) void k_agg(
    const unsigned short* __restrict__ xh, const unsigned short* __restrict__ xl,
    unsigned short* __restrict__ mh, unsigned short* __restrict__ ml, int SK,
    const int* __restrict__ row_ptr, const int* __restrict__ col, int n)
{
    int lane = threadIdx.x & 63;
    int node = blockIdx.x * 4 + (threadIdx.x >> 6);
    if (node >= n) return;
    node = __builtin_amdgcn_readfirstlane(node);
    int s = row_ptr[node], e = row_ptr[node + 1];
    int c2 = lane * 2;                 // two columns per lane
    float a0 = 0.f, a1 = 0.f;
    for (int p = s; p < e; ++p) {
        int sc = col[p];
        size_t o = (size_t)sc * SK + c2;
        unsigned int hh = *(const unsigned int*)(xh + o);
        unsigned int ll = *(const unsigned int*)(xl + o);
        a0 += __builtin_bit_cast(float, hh << 16) + __builtin_bit_cast(float, ll << 16);
        a1 += __builtin_bit_cast(float, hh & 0xffff0000u) + __builtin_bit_cast(float, ll & 0xffff0000u);
    }
    int deg = e - s;
    float inv = 1.f / (float)(deg > 1 ? deg : 1);
    a0 *= inv; a1 *= inv;
    unsigned short h0 = f2bf(a0), h1 = f2bf(a1);
    unsigned short l0 = f2bf(a0 - bf2f(h0)), l1 = f2bf(a1 - bf2f(h1));
    size_t o = (size_t)node * SK + c2;
    *(unsigned int*)(mh + o) = (unsigned int)h0 | ((unsigned int)h1 << 16);
    *(unsigned int*)(ml + o) = (unsigned int)l0 | ((unsigned int)l1 << 16);
}

// ---------------- generic split-bf16 MFMA GEMM, M-tile=64, block=256 ----------------
// A' row-major [m][SK], SK = 2*KT8*32 = [hi-half | lo-half].
// K-schedule, 3 branch-free fully-unrolled passes: (A_hi,W_hi), (A_lo,W_hi), (A_hi,W_lo).
// Epilogue in 2 phases of 32 rows (halves LDS -> 16.9 KB), 8 threads/row.
// EPI 0: out = relu(C+bias) -> pair store.  EPI 1: LN+relu, out = res + 0.5*r -> pair store.
// EPI 2: head: s = relu(C+bias)·wh2 + bh2 -> outp.
template<int NC, int KT8, int EPI>
__global__ __launch_bounds__(256, 4) void k_gemm(
    const unsigned short* __restrict__ A, int SK,
    const unsigned short* __restrict__ Whi, const unsigned short* __restrict__ Wlo,
    const float* __restrict__ bias,
    const float* __restrict__ g, const float* __restrict__ be,
    const unsigned short* __restrict__ SrcH, const unsigned short* __restrict__ SrcL, int SSK,
    unsigned short* __restrict__ DstH, unsigned short* __restrict__ DstL, int DSK,
    const float* __restrict__ wh2, const float* __restrict__ bh2, float* __restrict__ outp,
    int n)
{
    constexpr int NT = NC / 64;       // n-16-tiles per wave
    __shared__ float Cb[32][NC + 4];
    int t = threadIdx.x;
    int lane = t & 63, w = t >> 6;
    int l15 = lane & 15, kg = lane >> 4;
    int m0 = blockIdx.x * 64;

    size_t aoff[4];
    #pragma unroll
    for (int mt = 0; mt < 4; ++mt) {
        int r = m0 + mt * 16 + l15;
        r = r < n ? r : n - 1;
        aoff[mt] = (size_t)r * SK + kg * 8;
    }
    size_t nb[NT];
    #pragma unroll
    for (int nt = 0; nt < NT; ++nt)
        nb[nt] = (size_t)(w * (NC / 4) + nt * 16 + l15) * 32 + kg * 8;

    f32x4 acc[4][NT];
    #pragma unroll
    for (int mt = 0; mt < 4; ++mt)
        #pragma unroll
        for (int nt = 0; nt < NT; ++nt)
            acc[mt][nt] = (f32x4)(0.f);

    auto kstep = [&](int at, int wt, const unsigned short* __restrict__ Wp) {
        int koff = at * 32;
        short8 af[4];
        #pragma unroll
        for (int mt = 0; mt < 4; ++mt)
            af[mt] = *(const short8*)(A + aoff[mt] + koff);
        short8 bfr[NT];
        #pragma unroll
        for (int nt = 0; nt < NT; ++nt)
            bfr[nt] = *(const short8*)(Wp + (size_t)wt * NC * 32 + nb[nt]);
        #pragma unroll
        for (int mt = 0; mt < 4; ++mt)
            #pragma unroll
            for (int nt = 0; nt < NT; ++nt)
                acc[mt][nt] = __builtin_amdgcn_mfma_f32_16x16x32_bf16(af[mt], bfr[nt], acc[mt][nt], 0, 0, 0);
    };

    #pragma unroll
    for (int s = 0; s < KT8; ++s) kstep(s, s, Whi);          // A_hi · W_hi
    #pragma unroll
    for (int s = 0; s < KT8; ++s) kstep(KT8 + s, s, Whi);    // A_lo · W_hi
    #pragma unroll
    for (int s = 0; s < KT8; ++s) kstep(s, s, Wlo);          // A_hi · W_lo

    // Epilogue: two phases of 32 rows.  C/D layout: col = lane&15, row = quad*4 + reg.
    constexpr int CW = NC / 8;        // cols per epilogue thread (8 threads/row)
    int er = t >> 3, q = t & 7;
    int cb = q * CW;

    #pragma unroll
    for (int p = 0; p < 2; ++p) {
        if (p) __syncthreads();       // phase-0 readers done before overwrite
        #pragma unroll
        for (int mt2 = 0; mt2 < 2; ++mt2) {
            int mt = 2 * p + mt2;
            #pragma unroll
            for (int nt = 0; nt < NT; ++nt)
                #pragma unroll
                for (int r = 0; r < 4; ++r)
                    Cb[mt2 * 16 + kg * 4 + r][w * (NC / 4) + nt * 16 + l15] = acc[mt][nt][r];
        }
        __syncthreads();

        int gr = m0 + p * 32 + er;

        if (EPI == 0) {
            if (gr < n) {
                #pragma unroll
                for (int i = 0; i < CW / 4; ++i) {
                    int c = cb + 4 * i;
                    float4 v  = *(const float4*)&Cb[er][c];
                    float4 bi = *(const float4*)&bias[c];
                    float o0 = fmaxf(v.x + bi.x, 0.f), o1 = fmaxf(v.y + bi.y, 0.f);
                    float o2 = fmaxf(v.z + bi.z, 0.f), o3 = fmaxf(v.w + bi.w, 0.f);
                    unsigned short h0 = f2bf(o0), h1 = f2bf(o1), h2 = f2bf(o2), h3 = f2bf(o3);
                    ushort4 hv = make_ushort4(h0, h1, h2, h3);
                    ushort4 lv = make_ushort4(f2bf(o0 - bf2f(h0)), f2bf(o1 - bf2f(h1)),
                                              f2bf(o2 - bf2f(h2)), f2bf(o3 - bf2f(h3)));
                    *(ushort4*)(DstH + (size_t)gr * DSK + c) = hv;
                    *(ushort4*)(DstL + (size_t)gr * DSK + c) = lv;
                }
            }
        } else if (EPI == 1) {
            float s = 0.f, ss = 0.f;
            #pragma unroll
            for (int i = 0; i < CW / 4; ++i) {
                int c = cb + 4 * i;
                float4 v  = *(const float4*)&Cb[er][c];
                float4 bi = *(const float4*)&bias[c];
                float a0 = v.x + bi.x, a1 = v.y + bi.y, a2 = v.z + bi.z, a3 = v.w + bi.w;
                s  += a0 + a1 + a2 + a3;
                ss += a0 * a0 + a1 * a1 + a2 * a2 + a3 * a3;
            }
            s  += __shfl_xor(s, 1);  s  += __shfl_xor(s, 2);  s  += __shfl_xor(s, 4);
            ss += __shfl_xor(ss, 1); ss += __shfl_xor(ss, 2); ss += __shfl_xor(ss, 4);
            float mu  = s * (1.f / NC);
            float var = ss * (1.f / NC) - mu * mu;
            float rs  = rsqrtf(var + 1e-5f);
            if (gr < n) {
                #pragma unroll
                for (int i = 0; i < CW / 4; ++i) {
                    int c = cb + 4 * i;
                    float4 v  = *(const float4*)&Cb[er][c];
                    float4 bi = *(const float4*)&bias[c];
                    float4 gg = *(const float4*)&g[c];
                    float4 bb = *(const float4*)&be[c];
                    float r0 = fmaxf((v.x + bi.x - mu) * rs * gg.x + bb.x, 0.f);
                    float r1 = fmaxf((v.y + bi.y - mu) * rs * gg.y + bb.y, 0.f);
                    float r2 = fmaxf((v.z + bi.z - mu) * rs * gg.z + bb.z, 0.f);
                    float r3 = fmaxf((v.w + bi.w - mu) * rs * gg.w + bb.w, 0.f);
                    ushort4 rh = *(const ushort4*)(SrcH + (size_t)gr * SSK + c);
                    ushort4 rl = *(const ushort4*)(SrcL + (size_t)gr * SSK + c);
                    float o0 = bf2f(rh.x) + bf2f(rl.x) + 0.5f * r0;
                    float o1 = bf2f(rh.y) + bf2f(rl.y) + 0.5f * r1;
                    float o2 = bf2f(rh.z) + bf2f(rl.z) + 0.5f * r2;
                    float o3 = bf2f(rh.w) + bf2f(rl.w) + 0.5f * r3;
                    unsigned short h0 = f2bf(o0), h1 = f2bf(o1), h2 = f2bf(o2), h3 = f2bf(o3);
                    ushort4 hv = make_ushort4(h0, h1, h2, h3);
                    ushort4 lv = make_ushort4(f2bf(o0 - bf2f(h0)), f2bf(o1 - bf2f(h1)),
                                              f2bf(o2 - bf2f(h2)), f2bf(o3 - bf2f(h3)));
                    *(ushort4*)(DstH + (size_t)gr * DSK + c) = hv;
                    *(ushort4*)(DstL + (size_t)gr * DSK + c) = lv;
                }
            }
        } else {
            float s = 0.f;
            #pragma unroll
            for (int i = 0; i < CW / 4; ++i) {
                int c = cb + 4 * i;
                float4 v  = *(const float4*)&Cb[er][c];
                float4 bi = *(const float4*)&bias[c];
                float4 w2 = *(const float4*)&wh2[c];
                s += fmaxf(v.x + bi.x, 0.f) * w2.x + fmaxf(v.y + bi.y, 0.f) * w2.y
                   + fmaxf(v.z + bi.z, 0.f) * w2.z + fmaxf(v.w + bi.w, 0.f) * w2.w;
            }
            s += __shfl_xor(s, 1); s += __shfl_xor(s, 2); s += __shfl_xor(s, 4);
            if (q == 0 && gr < n) outp[gr] = s + bh2[0];
        }
    }
}

// ---------------- launcher ----------------
extern "C" void kernel_launch(void* const* d_in, const int* in_sizes, int n_in,
                              void* d_out, int out_size, void* d_ws, size_t ws_size,
                              hipStream_t stream)
{
    const float* xnum = (const float*)d_in[0];
    const int*   xcat = (const int*)d_in[1];
    const int*   eidx = (const int*)d_in[2];
    const float* e0   = (const float*)d_in[3];
    const float* e1   = (const float*)d_in[4];
    const float* e2   = (const float*)d_in[5];
    const float* e3   = (const float*)d_in[6];
    const float* w_in = (const float*)d_in[7];
    const float* b_in = (const float*)d_in[8];
    const float* w1l  = (const float*)d_in[9];
    const float* b1l  = (const float*)d_in[10];
    const float* w1r  = (const float*)d_in[11];
    const float* w2l  = (const float*)d_in[12];
    const float* b2l  = (const float*)d_in[13];
    const float* w2r  = (const float*)d_in[14];
    const float* g1   = (const float*)d_in[15];
    const float* be1  = (const float*)d_in[16];
    const float* g2   = (const float*)d_in[17];
    const float* be2  = (const float*)d_in[18];
    const float* wh1  = (const float*)d_in[19];
    const float* bh1  = (const float*)d_in[20];
    const float* wh2  = (const float*)d_in[21];
    const float* bh2  = (const float*)d_in[22];

    int n = in_sizes[0] / 32;
    int ecount = in_sizes[2] / 2;
    const int* esrc = eidx;
    const int* edst = eidx + ecount;

    char* ws = (char*)d_ws;
    size_t off = 0;
    auto alloc = [&](size_t bytes) -> void* {
        void* p = ws + off;
        off += (bytes + 255) & ~(size_t)255;
        return p;
    };
    // Region R0: A1 (n x 512 pairs) ; A3 (n x 256) aliases it (A1 dead after conv1).
    unsigned short* A1 = (unsigned short*)alloc((size_t)n * 512 * 2);
    unsigned short* A3 = A1;
    // Region R1: A2 (n x 512) ; A0 (n x 192) aliases it (A0 dead before conv1 epilogue writes A2).
    unsigned short* A2 = (unsigned short*)alloc((size_t)n * 512 * 2);
    unsigned short* A0 = A2;
    // Weight fragment buffers
    unsigned short* w0h = (unsigned short*)alloc((size_t)96 * 128 * 2);
    unsigned short* w0l = (unsigned short*)alloc((size_t)96 * 128 * 2);
    unsigned short* w1h = (unsigned short*)alloc((size_t)256 * 128 * 2);
    unsigned short* w1lo= (unsigned short*)alloc((size_t)256 * 128 * 2);
    unsigned short* w2h = (unsigned short*)alloc((size_t)256 * 128 * 2);
    unsigned short* w2lo= (unsigned short*)alloc((size_t)256 * 128 * 2);
    unsigned short* whh = (unsigned short*)alloc((size_t)128 * 64 * 2);
    unsigned short* whl = (unsigned short*)alloc((size_t)128 * 64 * 2);
    // CSR
    int* cnt     = (int*)alloc((size_t)n * 4);
    int* row_ptr = (int*)alloc((size_t)(n + 1) * 4);
    int* cursor  = (int*)alloc((size_t)n * 4);
    int* col     = (int*)alloc((size_t)ecount * 4);
    int nb1 = (n + 4095) / 4096;
    int* bsum    = (int*)alloc((size_t)nb1 * 4);
    (void)ws_size; (void)n_in; (void)out_size;

    int gemmBlocks = (n + 63) / 64;
    int gridE = 2048;
    int aggBlocks = (n + 3) / 4;

    // weight prep
    k_prepw<<<(96 * 128 + 255) / 256, 256, 0, stream>>>(w_in, 71, nullptr, 0, 96, 128, w0h, w0l);
    k_prepw<<<(256 * 128 + 255) / 256, 256, 0, stream>>>(w1l, 128, w1r, 128, 256, 128, w1h, w1lo);
    k_prepw<<<(256 * 128 + 255) / 256, 256, 0, stream>>>(w2l, 128, w2r, 128, 256, 128, w2h, w2lo);
    k_prepw<<<(128 * 64 + 255) / 256, 256, 0, stream>>>(wh1, 128, nullptr, 0, 128, 64, whh, whl);

    // input features -> A0
    k_stack0<<<((size_t)n * 6 + 255) / 256, 256, 0, stream>>>(xnum, xcat, e0, e1, e2, e3, A0, n);

    // CSR build (by dst)
    hipMemsetAsync(cnt, 0, (size_t)n * 4, stream);
    k_count<<<gridE, 256, 0, stream>>>(edst, cnt, ecount);
    k_scan1<<<nb1, 1024, 0, stream>>>(cnt, row_ptr, bsum, n);
    k_scan2<<<1, 64, 0, stream>>>(bsum, nb1);
    k_scan3<<<(n + 255) / 256, 256, 0, stream>>>(row_ptr, bsum, cursor, n, ecount);
    k_fill<<<gridE, 256, 0, stream>>>(esrc, edst, cursor, col, ecount);

    // input MLP: A0[192] @ W0 -> x0 pairs into A1 x-slots (hi@128, lo@384)
    k_gemm<128, 3, 0><<<gemmBlocks, 256, 0, stream>>>(
        A0, 192, w0h, w0l, b_in,
        nullptr, nullptr, nullptr, nullptr, 0,
        A1 + 128, A1 + 384, 512,
        nullptr, nullptr, nullptr, n);

    // conv1: mean of x0 -> A1 mean-slots; GEMM A1[512] @ [w1l;w1r] -> x1 pairs -> A2 x-slots
    k_agg<<<aggBlocks, 256, 0, stream>>>(A1 + 128, A1 + 384, A1, A1 + 256, 512, row_ptr, col, n);
    k_gemm<128, 8, 1><<<gemmBlocks, 256, 0, stream>>>(
        A1, 512, w1h, w1lo, b1l,
        g1, be1, A1 + 128, A1 + 384, 512,
        A2 + 128, A2 + 384, 512,
        nullptr, nullptr, nullptr, n);

    // conv2: mean of x1 -> A2 mean-slots; GEMM A2[512] -> x2 pairs -> A3 (hi@0, lo@128)
    k_agg<<<aggBlocks, 256, 0, stream>>>(A2 + 128, A2 + 384, A2, A2 + 256, 512, row_ptr, col, n);
    k_gemm<128, 8, 1><<<gemmBlocks, 256, 0, stream>>>(
        A2, 512, w2h, w2lo, b2l,
        g2, be2, A2 + 128, A2 + 384, 512,
        A3, A3 + 128, 256,
        nullptr, nullptr, nullptr, n);

    // head: A3[256] @ wh1 -> relu -> ·wh2 + bh2 -> out
    k_gemm<64, 4, 2><<<gemmBlocks, 256, 0, stream>>>(
        A3, 256, whh, whl, bh1,
        nullptr, nullptr, nullptr, nullptr, 0,
        nullptr, nullptr, 0,
        wh2, bh2, (float*)d_out, n);
}

// Round 6
// 808.515 us; speedup vs baseline: 1.2286x; 1.2286x over previous
//
#include <hip/hip_runtime.h>

#define HID 128

typedef __attribute__((ext_vector_type(8))) short short8;
typedef __attribute__((ext_vector_type(4))) float f32x4;

__device__ __forceinline__ float bf2f(unsigned short u) {
    unsigned int x = ((unsigned int)u) << 16;
    return __builtin_bit_cast(float, x);
}
__device__ __forceinline__ unsigned short f2bf(float f) {
    unsigned int u = __builtin_bit_cast(unsigned int, f);
    u += 0x7fffu + ((u >> 16) & 1u);
    return (unsigned short)(u >> 16);
}

// ---------------- weight prep: fp32 [K,N] (optionally two stacked sources) ->
// fragment layout hi/lo: elem (k,n) at ((k/32)*N + n)*32 + k%32 ----------------
__global__ __launch_bounds__(256) void k_prepw(const float* __restrict__ s1, int k1,
    const float* __restrict__ s2, int k2, int Kp, int N,
    unsigned short* __restrict__ whi, unsigned short* __restrict__ wlo)
{
    int i = blockIdx.x * 256 + threadIdx.x;
    if (i >= Kp * N) return;
    int k = i / N, nn = i - k * N;
    float v = 0.f;
    if (k < k1) v = s1[(size_t)k * N + nn];
    else if (k < k1 + k2) v = s2[(size_t)(k - k1) * N + nn];
    unsigned short h = f2bf(v);
    unsigned short l = f2bf(v - bf2f(h));
    size_t o = ((size_t)(k >> 5) * N + nn) * 32 + (k & 31);
    whi[o] = h; wlo[o] = l;
}

// ---------------- input feature prestack: [xnum | emb0..3 | pad] -> bf16 hi/lo pairs,
// A0 row-major [n][192] = [hi(96) | lo(96)].  6 chunks of 16 cols per row. ----------------
__global__ __launch_bounds__(256) void k_stack0(
    const float* __restrict__ xnum, const int* __restrict__ xcat,
    const float* __restrict__ e0, const float* __restrict__ e1,
    const float* __restrict__ e2, const float* __restrict__ e3,
    unsigned short* __restrict__ A0, int n)
{
    int g = blockIdx.x * 256 + threadIdx.x;
    int r = g / 6, c = g - r * 6;              // 6 chunks of 16 cols (96 features)
    if (r >= n) return;
    int4 cc = ((const int4*)xcat)[r];
    float v[16];
    int base = c * 16;
    #pragma unroll
    for (int j = 0; j < 16; ++j) {
        int col = base + j;
        float val;
        if      (col < 32) val = xnum[(size_t)r * 32 + col];
        else if (col < 42) val = e0[(size_t)cc.x * 10 + (col - 32)];
        else if (col < 48) val = e1[(size_t)cc.y * 6  + (col - 42)];
        else if (col < 53) val = e2[(size_t)cc.z * 5  + (col - 48)];
        else if (col < 71) val = e3[(size_t)cc.w * 18 + (col - 53)];
        else               val = 0.f;
        v[j] = val;
    }
    unsigned int ph[8], pl[8];
    #pragma unroll
    for (int j = 0; j < 8; ++j) {
        unsigned short h0 = f2bf(v[2*j]),   h1 = f2bf(v[2*j+1]);
        unsigned short l0 = f2bf(v[2*j]   - bf2f(h0));
        unsigned short l1 = f2bf(v[2*j+1] - bf2f(h1));
        ph[j] = (unsigned int)h0 | ((unsigned int)h1 << 16);
        pl[j] = (unsigned int)l0 | ((unsigned int)l1 << 16);
    }
    unsigned int* dh = (unsigned int*)(A0 + (size_t)r * 192 + base);
    unsigned int* dl = (unsigned int*)(A0 + (size_t)r * 192 + 96 + base);
    uint4 a; a.x = ph[0]; a.y = ph[1]; a.z = ph[2]; a.w = ph[3];
    uint4 b; b.x = ph[4]; b.y = ph[5]; b.z = ph[6]; b.w = ph[7];
    ((uint4*)dh)[0] = a; ((uint4*)dh)[1] = b;
    a.x = pl[0]; a.y = pl[1]; a.z = pl[2]; a.w = pl[3];
    b.x = pl[4]; b.y = pl[5]; b.z = pl[6]; b.w = pl[7];
    ((uint4*)dl)[0] = a; ((uint4*)dl)[1] = b;
}

// ---------------- CSR build ----------------
__global__ __launch_bounds__(256) void k_count(const int* __restrict__ dst,
                                               int* __restrict__ cnt, int ecount)
{
    int i = blockIdx.x * blockDim.x + threadIdx.x;
    int stride = gridDim.x * blockDim.x;
    for (; i < ecount; i += stride) atomicAdd(&cnt[dst[i]], 1);
}

__global__ __launch_bounds__(1024) void k_scan1(const int* __restrict__ cnt,
    int* __restrict__ excl, int* __restrict__ bsum, int n)
{
    __shared__ int sm[1024];
    int t = threadIdx.x;
    int base = blockIdx.x * 4096 + t * 4;
    int v0 = (base + 0 < n) ? cnt[base + 0] : 0;
    int v1 = (base + 1 < n) ? cnt[base + 1] : 0;
    int v2 = (base + 2 < n) ? cnt[base + 2] : 0;
    int v3 = (base + 3 < n) ? cnt[base + 3] : 0;
    int s = v0 + v1 + v2 + v3;
    sm[t] = s;
    __syncthreads();
    for (int offd = 1; offd < 1024; offd <<= 1) {
        int tv = (t >= offd) ? sm[t - offd] : 0;
        __syncthreads();
        sm[t] += tv;
        __syncthreads();
    }
    int incl = sm[t];
    int ex = incl - s;
    if (t == 1023) bsum[blockIdx.x] = incl;
    if (base + 0 < n) excl[base + 0] = ex; ex += v0;
    if (base + 1 < n) excl[base + 1] = ex; ex += v1;
    if (base + 2 < n) excl[base + 2] = ex; ex += v2;
    if (base + 3 < n) excl[base + 3] = ex;
}

__global__ void k_scan2(int* __restrict__ bsum, int nb)
{
    if (threadIdx.x == 0 && blockIdx.x == 0) {
        int run = 0;
        for (int i = 0; i < nb; ++i) { int t = bsum[i]; bsum[i] = run; run += t; }
    }
}

__global__ __launch_bounds__(256) void k_scan3(int* __restrict__ row_ptr,
    const int* __restrict__ bsum, int* __restrict__ cursor, int n, int ecount)
{
    int i = blockIdx.x * 256 + threadIdx.x;
    if (i < n) {
        int v = row_ptr[i] + bsum[i >> 12];
        row_ptr[i] = v;
        cursor[i] = v;
    }
    if (i == 0) row_ptr[n] = ecount;
}

__global__ __launch_bounds__(256) void k_fill(const int* __restrict__ src,
    const int* __restrict__ dst, int* __restrict__ cursor,
    int* __restrict__ col, int ecount)
{
    int i = blockIdx.x * blockDim.x + threadIdx.x;
    int stride = gridDim.x * blockDim.x;
    for (; i < ecount; i += stride) {
        int d = dst[i];
        int slot = atomicAdd(&cursor[d], 1);
        col[slot] = src[i];
    }
}

// ---------------- mean aggregation over bf16 pairs: one wave per node ----------------
__global__ __launch_bounds__(256) void k_agg(
    const unsigned short* __restrict__ xh, const unsigned short* __restrict__ xl,
    unsigned short* __restrict__ mh, unsigned short* __restrict__ ml, int SK,
    const int* __restrict__ row_ptr, const int* __restrict__ col, int n)
{
    int lane = threadIdx.x & 63;
    int node = blockIdx.x * 4 + (threadIdx.x >> 6);
    if (node >= n) return;
    node = __builtin_amdgcn_readfirstlane(node);
    int s = row_ptr[node], e = row_ptr[node + 1];
    int c2 = lane * 2;                 // two columns per lane
    float a0 = 0.f, a1 = 0.f;
    for (int p = s; p < e; ++p) {
        int sc = col[p];
        size_t o = (size_t)sc * SK + c2;
        unsigned int hh = *(const unsigned int*)(xh + o);
        unsigned int ll = *(const unsigned int*)(xl + o);
        a0 += __builtin_bit_cast(float, hh << 16) + __builtin_bit_cast(float, ll << 16);
        a1 += __builtin_bit_cast(float, hh & 0xffff0000u) + __builtin_bit_cast(float, ll & 0xffff0000u);
    }
    int deg = e - s;
    float inv = 1.f / (float)(deg > 1 ? deg : 1);
    a0 *= inv; a1 *= inv;
    unsigned short h0 = f2bf(a0), h1 = f2bf(a1);
    unsigned short l0 = f2bf(a0 - bf2f(h0)), l1 = f2bf(a1 - bf2f(h1));
    size_t o = (size_t)node * SK + c2;
    *(unsigned int*)(mh + o) = (unsigned int)h0 | ((unsigned int)h1 << 16);
    *(unsigned int*)(ml + o) = (unsigned int)l0 | ((unsigned int)l1 << 16);
}

// ---------------- generic split-bf16 MFMA GEMM, M-tile=64, block=256 ----------------
// A' row-major [m][SK], SK = 2*KT8*32 = [hi-half | lo-half].
// Merged K-loop (#pragma unroll 1, ~110 VGPR — NO spills): per k-tile s load
// A_hi,A_lo,W_hi,W_lo once, issue 3 MFMA groups (Ah·Wh, Al·Wh, Ah·Wl).
// Epilogue in 2 phases of 32 rows (LDS 16.9 KB), 8 threads/row.
// EPI 0: out = relu(C+bias) -> pair store.  EPI 1: LN+relu, out = res + 0.5*r -> pair store.
// EPI 2: head: s = relu(C+bias)·wh2 + bh2 -> outp.
template<int NC, int KT8, int EPI>
__global__ __launch_bounds__(256) void k_gemm(
    const unsigned short* __restrict__ A, int SK,
    const unsigned short* __restrict__ Whi, const unsigned short* __restrict__ Wlo,
    const float* __restrict__ bias,
    const float* __restrict__ g, const float* __restrict__ be,
    const unsigned short* __restrict__ SrcH, const unsigned short* __restrict__ SrcL, int SSK,
    unsigned short* __restrict__ DstH, unsigned short* __restrict__ DstL, int DSK,
    const float* __restrict__ wh2, const float* __restrict__ bh2, float* __restrict__ outp,
    int n)
{
    constexpr int NT = NC / 64;       // n-16-tiles per wave
    __shared__ float Cb[32][NC + 4];
    int t = threadIdx.x;
    int lane = t & 63, w = t >> 6;
    int l15 = lane & 15, kg = lane >> 4;
    int m0 = blockIdx.x * 64;

    size_t aoff[4];
    #pragma unroll
    for (int mt = 0; mt < 4; ++mt) {
        int r = m0 + mt * 16 + l15;
        r = r < n ? r : n - 1;
        aoff[mt] = (size_t)r * SK + kg * 8;
    }
    size_t nb[NT];
    #pragma unroll
    for (int nt = 0; nt < NT; ++nt)
        nb[nt] = (size_t)(w * (NC / 4) + nt * 16 + l15) * 32 + kg * 8;

    f32x4 acc[4][NT];
    #pragma unroll
    for (int mt = 0; mt < 4; ++mt)
        #pragma unroll
        for (int nt = 0; nt < NT; ++nt)
            acc[mt][nt] = (f32x4)(0.f);

    #pragma unroll 1
    for (int s = 0; s < KT8; ++s) {
        int koff = s * 32;
        short8 ah[4], al[4];
        #pragma unroll
        for (int mt = 0; mt < 4; ++mt) {
            ah[mt] = *(const short8*)(A + aoff[mt] + koff);
            al[mt] = *(const short8*)(A + aoff[mt] + KT8 * 32 + koff);
        }
        short8 bh[NT], bl[NT];
        #pragma unroll
        for (int nt = 0; nt < NT; ++nt) {
            bh[nt] = *(const short8*)(Whi + (size_t)s * NC * 32 + nb[nt]);
            bl[nt] = *(const short8*)(Wlo + (size_t)s * NC * 32 + nb[nt]);
        }
        #pragma unroll
        for (int mt = 0; mt < 4; ++mt)
            #pragma unroll
            for (int nt = 0; nt < NT; ++nt)
                acc[mt][nt] = __builtin_amdgcn_mfma_f32_16x16x32_bf16(ah[mt], bh[nt], acc[mt][nt], 0, 0, 0);
        #pragma unroll
        for (int mt = 0; mt < 4; ++mt)
            #pragma unroll
            for (int nt = 0; nt < NT; ++nt)
                acc[mt][nt] = __builtin_amdgcn_mfma_f32_16x16x32_bf16(al[mt], bh[nt], acc[mt][nt], 0, 0, 0);
        #pragma unroll
        for (int mt = 0; mt < 4; ++mt)
            #pragma unroll
            for (int nt = 0; nt < NT; ++nt)
                acc[mt][nt] = __builtin_amdgcn_mfma_f32_16x16x32_bf16(ah[mt], bl[nt], acc[mt][nt], 0, 0, 0);
    }

    // Epilogue: two phases of 32 rows.  C/D layout: col = lane&15, row = quad*4 + reg.
    constexpr int CW = NC / 8;        // cols per epilogue thread (8 threads/row)
    int er = t >> 3, q = t & 7;
    int cb = q * CW;

    #pragma unroll
    for (int p = 0; p < 2; ++p) {
        if (p) __syncthreads();       // phase-0 readers done before overwrite
        #pragma unroll
        for (int mt2 = 0; mt2 < 2; ++mt2) {
            int mt = 2 * p + mt2;
            #pragma unroll
            for (int nt = 0; nt < NT; ++nt)
                #pragma unroll
                for (int r = 0; r < 4; ++r)
                    Cb[mt2 * 16 + kg * 4 + r][w * (NC / 4) + nt * 16 + l15] = acc[mt][nt][r];
        }
        __syncthreads();

        int gr = m0 + p * 32 + er;

        if (EPI == 0) {
            if (gr < n) {
                #pragma unroll
                for (int i = 0; i < CW / 4; ++i) {
                    int c = cb + 4 * i;
                    float4 v  = *(const float4*)&Cb[er][c];
                    float4 bi = *(const float4*)&bias[c];
                    float o0 = fmaxf(v.x + bi.x, 0.f), o1 = fmaxf(v.y + bi.y, 0.f);
                    float o2 = fmaxf(v.z + bi.z, 0.f), o3 = fmaxf(v.w + bi.w, 0.f);
                    unsigned short h0 = f2bf(o0), h1 = f2bf(o1), h2 = f2bf(o2), h3 = f2bf(o3);
                    ushort4 hv = make_ushort4(h0, h1, h2, h3);
                    ushort4 lv = make_ushort4(f2bf(o0 - bf2f(h0)), f2bf(o1 - bf2f(h1)),
                                              f2bf(o2 - bf2f(h2)), f2bf(o3 - bf2f(h3)));
                    *(ushort4*)(DstH + (size_t)gr * DSK + c) = hv;
                    *(ushort4*)(DstL + (size_t)gr * DSK + c) = lv;
                }
            }
        } else if (EPI == 1) {
            float s = 0.f, ss = 0.f;
            #pragma unroll
            for (int i = 0; i < CW / 4; ++i) {
                int c = cb + 4 * i;
                float4 v  = *(const float4*)&Cb[er][c];
                float4 bi = *(const float4*)&bias[c];
                float a0 = v.x + bi.x, a1 = v.y + bi.y, a2 = v.z + bi.z, a3 = v.w + bi.w;
                s  += a0 + a1 + a2 + a3;
                ss += a0 * a0 + a1 * a1 + a2 * a2 + a3 * a3;
            }
            s  += __shfl_xor(s, 1);  s  += __shfl_xor(s, 2);  s  += __shfl_xor(s, 4);
            ss += __shfl_xor(ss, 1); ss += __shfl_xor(ss, 2); ss += __shfl_xor(ss, 4);
            float mu  = s * (1.f / NC);
            float var = ss * (1.f / NC) - mu * mu;
            float rs  = rsqrtf(var + 1e-5f);
            if (gr < n) {
                #pragma unroll
                for (int i = 0; i < CW / 4; ++i) {
                    int c = cb + 4 * i;
                    float4 v  = *(const float4*)&Cb[er][c];
                    float4 bi = *(const float4*)&bias[c];
                    float4 gg = *(const float4*)&g[c];
                    float4 bb = *(const float4*)&be[c];
                    float r0 = fmaxf((v.x + bi.x - mu) * rs * gg.x + bb.x, 0.f);
                    float r1 = fmaxf((v.y + bi.y - mu) * rs * gg.y + bb.y, 0.f);
                    float r2 = fmaxf((v.z + bi.z - mu) * rs * gg.z + bb.z, 0.f);
                    float r3 = fmaxf((v.w + bi.w - mu) * rs * gg.w + bb.w, 0.f);
                    ushort4 rh = *(const ushort4*)(SrcH + (size_t)gr * SSK + c);
                    ushort4 rl = *(const ushort4*)(SrcL + (size_t)gr * SSK + c);
                    float o0 = bf2f(rh.x) + bf2f(rl.x) + 0.5f * r0;
                    float o1 = bf2f(rh.y) + bf2f(rl.y) + 0.5f * r1;
                    float o2 = bf2f(rh.z) + bf2f(rl.z) + 0.5f * r2;
                    float o3 = bf2f(rh.w) + bf2f(rl.w) + 0.5f * r3;
                    unsigned short h0 = f2bf(o0), h1 = f2bf(o1), h2 = f2bf(o2), h3 = f2bf(o3);
                    ushort4 hv = make_ushort4(h0, h1, h2, h3);
                    ushort4 lv = make_ushort4(f2bf(o0 - bf2f(h0)), f2bf(o1 - bf2f(h1)),
                                              f2bf(o2 - bf2f(h2)), f2bf(o3 - bf2f(h3)));
                    *(ushort4*)(DstH + (size_t)gr * DSK + c) = hv;
                    *(ushort4*)(DstL + (size_t)gr * DSK + c) = lv;
                }
            }
        } else {
            float s = 0.f;
            #pragma unroll
            for (int i = 0; i < CW / 4; ++i) {
                int c = cb + 4 * i;
                float4 v  = *(const float4*)&Cb[er][c];
                float4 bi = *(const float4*)&bias[c];
                float4 w2 = *(const float4*)&wh2[c];
                s += fmaxf(v.x + bi.x, 0.f) * w2.x + fmaxf(v.y + bi.y, 0.f) * w2.y
                   + fmaxf(v.z + bi.z, 0.f) * w2.z + fmaxf(v.w + bi.w, 0.f) * w2.w;
            }
            s += __shfl_xor(s, 1); s += __shfl_xor(s, 2); s += __shfl_xor(s, 4);
            if (q == 0 && gr < n) outp[gr] = s + bh2[0];
        }
    }
}

// ---------------- launcher ----------------
extern "C" void kernel_launch(void* const* d_in, const int* in_sizes, int n_in,
                              void* d_out, int out_size, void* d_ws, size_t ws_size,
                              hipStream_t stream)
{
    const float* xnum = (const float*)d_in[0];
    const int*   xcat = (const int*)d_in[1];
    const int*   eidx = (const int*)d_in[2];
    const float* e0   = (const float*)d_in[3];
    const float* e1   = (const float*)d_in[4];
    const float* e2   = (const float*)d_in[5];
    const float* e3   = (const float*)d_in[6];
    const float* w_in = (const float*)d_in[7];
    const float* b_in = (const float*)d_in[8];
    const float* w1l  = (const float*)d_in[9];
    const float* b1l  = (const float*)d_in[10];
    const float* w1r  = (const float*)d_in[11];
    const float* w2l  = (const float*)d_in[12];
    const float* b2l  = (const float*)d_in[13];
    const float* w2r  = (const float*)d_in[14];
    const float* g1   = (const float*)d_in[15];
    const float* be1  = (const float*)d_in[16];
    const float* g2   = (const float*)d_in[17];
    const float* be2  = (const float*)d_in[18];
    const float* wh1  = (const float*)d_in[19];
    const float* bh1  = (const float*)d_in[20];
    const float* wh2  = (const float*)d_in[21];
    const float* bh2  = (const float*)d_in[22];

    int n = in_sizes[0] / 32;
    int ecount = in_sizes[2] / 2;
    const int* esrc = eidx;
    const int* edst = eidx + ecount;

    char* ws = (char*)d_ws;
    size_t off = 0;
    auto alloc = [&](size_t bytes) -> void* {
        void* p = ws + off;
        off += (bytes + 255) & ~(size_t)255;
        return p;
    };
    // Region R0: A1 (n x 512 pairs) ; A3 (n x 256) aliases it (A1 dead after conv1).
    unsigned short* A1 = (unsigned short*)alloc((size_t)n * 512 * 2);
    unsigned short* A3 = A1;
    // Region R1: A2 (n x 512) ; A0 (n x 192) aliases it (A0 dead before conv1 epilogue writes A2).
    unsigned short* A2 = (unsigned short*)alloc((size_t)n * 512 * 2);
    unsigned short* A0 = A2;
    // Weight fragment buffers
    unsigned short* w0h = (unsigned short*)alloc((size_t)96 * 128 * 2);
    unsigned short* w0l = (unsigned short*)alloc((size_t)96 * 128 * 2);
    unsigned short* w1h = (unsigned short*)alloc((size_t)256 * 128 * 2);
    unsigned short* w1lo= (unsigned short*)alloc((size_t)256 * 128 * 2);
    unsigned short* w2h = (unsigned short*)alloc((size_t)256 * 128 * 2);
    unsigned short* w2lo= (unsigned short*)alloc((size_t)256 * 128 * 2);
    unsigned short* whh = (unsigned short*)alloc((size_t)128 * 64 * 2);
    unsigned short* whl = (unsigned short*)alloc((size_t)128 * 64 * 2);
    // CSR
    int* cnt     = (int*)alloc((size_t)n * 4);
    int* row_ptr = (int*)alloc((size_t)(n + 1) * 4);
    int* cursor  = (int*)alloc((size_t)n * 4);
    int* col     = (int*)alloc((size_t)ecount * 4);
    int nb1 = (n + 4095) / 4096;
    int* bsum    = (int*)alloc((size_t)nb1 * 4);
    (void)ws_size; (void)n_in; (void)out_size;

    int gemmBlocks = (n + 63) / 64;
    int gridE = 2048;
    int aggBlocks = (n + 3) / 4;

    // weight prep
    k_prepw<<<(96 * 128 + 255) / 256, 256, 0, stream>>>(w_in, 71, nullptr, 0, 96, 128, w0h, w0l);
    k_prepw<<<(256 * 128 + 255) / 256, 256, 0, stream>>>(w1l, 128, w1r, 128, 256, 128, w1h, w1lo);
    k_prepw<<<(256 * 128 + 255) / 256, 256, 0, stream>>>(w2l, 128, w2r, 128, 256, 128, w2h, w2lo);
    k_prepw<<<(128 * 64 + 255) / 256, 256, 0, stream>>>(wh1, 128, nullptr, 0, 128, 64, whh, whl);

    // input features -> A0
    k_stack0<<<((size_t)n * 6 + 255) / 256, 256, 0, stream>>>(xnum, xcat, e0, e1, e2, e3, A0, n);

    // CSR build (by dst)
    hipMemsetAsync(cnt, 0, (size_t)n * 4, stream);
    k_count<<<gridE, 256, 0, stream>>>(edst, cnt, ecount);
    k_scan1<<<nb1, 1024, 0, stream>>>(cnt, row_ptr, bsum, n);
    k_scan2<<<1, 64, 0, stream>>>(bsum, nb1);
    k_scan3<<<(n + 255) / 256, 256, 0, stream>>>(row_ptr, bsum, cursor, n, ecount);
    k_fill<<<gridE, 256, 0, stream>>>(esrc, edst, cursor, col, ecount);

    // input MLP: A0[192] @ W0 -> x0 pairs into A1 x-slots (hi@128, lo@384)
    k_gemm<128, 3, 0><<<gemmBlocks, 256, 0, stream>>>(
        A0, 192, w0h, w0l, b_in,
        nullptr, nullptr, nullptr, nullptr, 0,
        A1 + 128, A1 + 384, 512,
        nullptr, nullptr, nullptr, n);

    // conv1: mean of x0 -> A1 mean-slots; GEMM A1[512] @ [w1l;w1r] -> x1 pairs -> A2 x-slots
    k_agg<<<aggBlocks, 256, 0, stream>>>(A1 + 128, A1 + 384, A1, A1 + 256, 512, row_ptr, col, n);
    k_gemm<128, 8, 1><<<gemmBlocks, 256, 0, stream>>>(
        A1, 512, w1h, w1lo, b1l,
        g1, be1, A1 + 128, A1 + 384, 512,
        A2 + 128, A2 + 384, 512,
        nullptr, nullptr, nullptr, n);

    // conv2: mean of x1 -> A2 mean-slots; GEMM A2[512] -> x2 pairs -> A3 (hi@0, lo@128)
    k_agg<<<aggBlocks, 256, 0, stream>>>(A2 + 128, A2 + 384, A2, A2 + 256, 512, row_ptr, col, n);
    k_gemm<128, 8, 1><<<gemmBlocks, 256, 0, stream>>>(
        A2, 512, w2h, w2lo, b2l,
        g2, be2, A2 + 128, A2 + 384, 512,
        A3, A3 + 128, 256,
        nullptr, nullptr, nullptr, n);

    // head: A3[256] @ wh1 -> relu -> ·wh2 + bh2 -> out
    k_gemm<64, 4, 2><<<gemmBlocks, 256, 0, stream>>>(
        A3, 256, whh, whl, bh1,
        nullptr, nullptr, nullptr, nullptr, 0,
        nullptr, nullptr, 0,
        wh2, bh2, (float*)d_out, n);
}

// Round 7
// 652.209 us; speedup vs baseline: 1.5231x; 1.2397x over previous
//
#include <hip/hip_runtime.h>

#define HID 128

typedef __attribute__((ext_vector_type(8))) short short8;
typedef __attribute__((ext_vector_type(4))) float f32x4;

__device__ __forceinline__ float bf2f(unsigned short u) {
    unsigned int x = ((unsigned int)u) << 16;
    return __builtin_bit_cast(float, x);
}
__device__ __forceinline__ unsigned short f2bf(float f) {
    unsigned int u = __builtin_bit_cast(unsigned int, f);
    u += 0x7fffu + ((u >> 16) & 1u);
    return (unsigned short)(u >> 16);
}

// ---------------- weight prep: fp32 [K,N] (optionally two stacked sources) ->
// fragment layout hi/lo: elem (k,n) at ((k/32)*N + n)*32 + k%32 ----------------
__global__ __launch_bounds__(256) void k_prepw(const float* __restrict__ s1, int k1,
    const float* __restrict__ s2, int k2, int Kp, int N,
    unsigned short* __restrict__ whi, unsigned short* __restrict__ wlo)
{
    int i = blockIdx.x * 256 + threadIdx.x;
    if (i >= Kp * N) return;
    int k = i / N, nn = i - k * N;
    float v = 0.f;
    if (k < k1) v = s1[(size_t)k * N + nn];
    else if (k < k1 + k2) v = s2[(size_t)(k - k1) * N + nn];
    unsigned short h = f2bf(v);
    unsigned short l = f2bf(v - bf2f(h));
    size_t o = ((size_t)(k >> 5) * N + nn) * 32 + (k & 31);
    whi[o] = h; wlo[o] = l;
}

// ---------------- input feature prestack: [xnum | emb0..3 | pad] -> bf16 hi/lo pairs,
// A0 row-major [n][192] = [hi(96) | lo(96)].  6 chunks of 16 cols per row. ----------------
__global__ __launch_bounds__(256) void k_stack0(
    const float* __restrict__ xnum, const int* __restrict__ xcat,
    const float* __restrict__ e0, const float* __restrict__ e1,
    const float* __restrict__ e2, const float* __restrict__ e3,
    unsigned short* __restrict__ A0, int n)
{
    int g = blockIdx.x * 256 + threadIdx.x;
    int r = g / 6, c = g - r * 6;              // 6 chunks of 16 cols (96 features)
    if (r >= n) return;
    int4 cc = ((const int4*)xcat)[r];
    float v[16];
    int base = c * 16;
    #pragma unroll
    for (int j = 0; j < 16; ++j) {
        int col = base + j;
        float val;
        if      (col < 32) val = xnum[(size_t)r * 32 + col];
        else if (col < 42) val = e0[(size_t)cc.x * 10 + (col - 32)];
        else if (col < 48) val = e1[(size_t)cc.y * 6  + (col - 42)];
        else if (col < 53) val = e2[(size_t)cc.z * 5  + (col - 48)];
        else if (col < 71) val = e3[(size_t)cc.w * 18 + (col - 53)];
        else               val = 0.f;
        v[j] = val;
    }
    unsigned int ph[8], pl[8];
    #pragma unroll
    for (int j = 0; j < 8; ++j) {
        unsigned short h0 = f2bf(v[2*j]),   h1 = f2bf(v[2*j+1]);
        unsigned short l0 = f2bf(v[2*j]   - bf2f(h0));
        unsigned short l1 = f2bf(v[2*j+1] - bf2f(h1));
        ph[j] = (unsigned int)h0 | ((unsigned int)h1 << 16);
        pl[j] = (unsigned int)l0 | ((unsigned int)l1 << 16);
    }
    unsigned int* dh = (unsigned int*)(A0 + (size_t)r * 192 + base);
    unsigned int* dl = (unsigned int*)(A0 + (size_t)r * 192 + 96 + base);
    uint4 a; a.x = ph[0]; a.y = ph[1]; a.z = ph[2]; a.w = ph[3];
    uint4 b; b.x = ph[4]; b.y = ph[5]; b.z = ph[6]; b.w = ph[7];
    ((uint4*)dh)[0] = a; ((uint4*)dh)[1] = b;
    a.x = pl[0]; a.y = pl[1]; a.z = pl[2]; a.w = pl[3];
    b.x = pl[4]; b.y = pl[5]; b.z = pl[6]; b.w = pl[7];
    ((uint4*)dl)[0] = a; ((uint4*)dl)[1] = b;
}

// ---------------- CSR build: rank (atomics paid once) + scan + atomic-free place ----------------
__global__ __launch_bounds__(256) void k_rank(const int* __restrict__ dst,
    int* __restrict__ cnt, int* __restrict__ rank, int ecount)
{
    int i = blockIdx.x * blockDim.x + threadIdx.x;
    int stride = gridDim.x * blockDim.x;
    for (; i < ecount; i += stride)
        rank[i] = atomicAdd(&cnt[dst[i]], 1);
}

__global__ __launch_bounds__(1024) void k_scan1(const int* __restrict__ cnt,
    int* __restrict__ excl, int* __restrict__ bsum, int n)
{
    __shared__ int sm[1024];
    int t = threadIdx.x;
    int base = blockIdx.x * 4096 + t * 4;
    int v0 = (base + 0 < n) ? cnt[base + 0] : 0;
    int v1 = (base + 1 < n) ? cnt[base + 1] : 0;
    int v2 = (base + 2 < n) ? cnt[base + 2] : 0;
    int v3 = (base + 3 < n) ? cnt[base + 3] : 0;
    int s = v0 + v1 + v2 + v3;
    sm[t] = s;
    __syncthreads();
    for (int offd = 1; offd < 1024; offd <<= 1) {
        int tv = (t >= offd) ? sm[t - offd] : 0;
        __syncthreads();
        sm[t] += tv;
        __syncthreads();
    }
    int incl = sm[t];
    int ex = incl - s;
    if (t == 1023) bsum[blockIdx.x] = incl;
    if (base + 0 < n) excl[base + 0] = ex; ex += v0;
    if (base + 1 < n) excl[base + 1] = ex; ex += v1;
    if (base + 2 < n) excl[base + 2] = ex; ex += v2;
    if (base + 3 < n) excl[base + 3] = ex;
}

__global__ void k_scan2(int* __restrict__ bsum, int nb)
{
    if (threadIdx.x == 0 && blockIdx.x == 0) {
        int run = 0;
        for (int i = 0; i < nb; ++i) { int t = bsum[i]; bsum[i] = run; run += t; }
    }
}

__global__ __launch_bounds__(256) void k_scan3(int* __restrict__ row_ptr,
    const int* __restrict__ bsum, int n, int ecount)
{
    int i = blockIdx.x * 256 + threadIdx.x;
    if (i < n)
        row_ptr[i] = row_ptr[i] + bsum[i >> 12];
    if (i == 0) row_ptr[n] = ecount;
}

// node-range-grouped placement: group g = blockIdx&7 handles nodes [g*per8,(g+1)*per8)
// -> each group's col region (~E/8*4B ~ 800 KB) stays L2-resident, written back once.
__global__ __launch_bounds__(256) void k_place(const int* __restrict__ src,
    const int* __restrict__ dst, const int* __restrict__ rank,
    const int* __restrict__ row_ptr, int* __restrict__ col, int ecount, int n)
{
    int g  = blockIdx.x & 7;
    int per8 = (n + 7) >> 3;
    int lo = g * per8;
    int hi = lo + per8 < n ? lo + per8 : n;
    int bl = blockIdx.x >> 3;
    int nb = gridDim.x >> 3;
    int i = bl * blockDim.x + threadIdx.x;
    int stride = nb * blockDim.x;
    for (; i < ecount; i += stride) {
        int d = dst[i];
        if (d >= lo && d < hi)
            col[row_ptr[d] + rank[i]] = src[i];
    }
}

// ---------------- mean aggregation, hi-only: one wave per node ----------------
__global__ __launch_bounds__(256) void k_agg(
    const unsigned short* __restrict__ xh, unsigned short* __restrict__ mh, int SK,
    const int* __restrict__ row_ptr, const int* __restrict__ col, int n)
{
    int lane = threadIdx.x & 63;
    int node = blockIdx.x * 4 + (threadIdx.x >> 6);
    if (node >= n) return;
    node = __builtin_amdgcn_readfirstlane(node);
    int s = row_ptr[node], e = row_ptr[node + 1];
    int c2 = lane * 2;                 // two columns per lane
    float a0 = 0.f, a1 = 0.f;
    for (int p = s; p < e; ++p) {
        int sc = col[p];
        unsigned int hh = *(const unsigned int*)(xh + (size_t)sc * SK + c2);
        a0 += __builtin_bit_cast(float, hh << 16);
        a1 += __builtin_bit_cast(float, hh & 0xffff0000u);
    }
    int deg = e - s;
    float inv = 1.f / (float)(deg > 1 ? deg : 1);
    a0 *= inv; a1 *= inv;
    unsigned short h0 = f2bf(a0), h1 = f2bf(a1);
    *(unsigned int*)(mh + (size_t)node * SK + c2) = (unsigned int)h0 | ((unsigned int)h1 << 16);
}

// ---------------- generic split-bf16 MFMA GEMM, M-tile=64, block=256 ----------------
// A' row-major [m][SK], SK = 2*KT8*32 = [hi-half | lo-half].
// First MT8 k-tiles have no valid lo (mean stored hi-only): skip the Al·Wh group there.
// Merged K-loop (#pragma unroll 1): per k-tile load fragments once, issue MFMA groups.
// Epilogue in 2 phases of 32 rows (LDS 16.9 KB), 8 threads/row.
// EPI 0: out = relu(C+bias) -> pair store.  EPI 1: LN+relu, out = res + 0.5*r -> pair store.
// EPI 2: head: s = relu(C+bias)·wh2 + bh2 -> outp.
template<int NC, int KT8, int MT8, int EPI>
__global__ __launch_bounds__(256) void k_gemm(
    const unsigned short* __restrict__ A, int SK,
    const unsigned short* __restrict__ Whi, const unsigned short* __restrict__ Wlo,
    const float* __restrict__ bias,
    const float* __restrict__ g, const float* __restrict__ be,
    const unsigned short* __restrict__ SrcH, const unsigned short* __restrict__ SrcL, int SSK,
    unsigned short* __restrict__ DstH, unsigned short* __restrict__ DstL, int DSK,
    const float* __restrict__ wh2, const float* __restrict__ bh2, float* __restrict__ outp,
    int n)
{
    constexpr int NT = NC / 64;       // n-16-tiles per wave
    __shared__ float Cb[32][NC + 4];
    int t = threadIdx.x;
    int lane = t & 63, w = t >> 6;
    int l15 = lane & 15, kg = lane >> 4;
    int m0 = blockIdx.x * 64;

    size_t aoff[4];
    #pragma unroll
    for (int mt = 0; mt < 4; ++mt) {
        int r = m0 + mt * 16 + l15;
        r = r < n ? r : n - 1;
        aoff[mt] = (size_t)r * SK + kg * 8;
    }
    size_t nb[NT];
    #pragma unroll
    for (int nt = 0; nt < NT; ++nt)
        nb[nt] = (size_t)(w * (NC / 4) + nt * 16 + l15) * 32 + kg * 8;

    f32x4 acc[4][NT];
    #pragma unroll
    for (int mt = 0; mt < 4; ++mt)
        #pragma unroll
        for (int nt = 0; nt < NT; ++nt)
            acc[mt][nt] = (f32x4)(0.f);

    // k-tiles [0, MT8): hi-only A (mean region) — groups Ah·Wh, Ah·Wl
    #pragma unroll 1
    for (int s = 0; s < MT8; ++s) {
        int koff = s * 32;
        short8 ah[4];
        #pragma unroll
        for (int mt = 0; mt < 4; ++mt)
            ah[mt] = *(const short8*)(A + aoff[mt] + koff);
        short8 bh[NT], bl[NT];
        #pragma unroll
        for (int nt = 0; nt < NT; ++nt) {
            bh[nt] = *(const short8*)(Whi + (size_t)s * NC * 32 + nb[nt]);
            bl[nt] = *(const short8*)(Wlo + (size_t)s * NC * 32 + nb[nt]);
        }
        #pragma unroll
        for (int mt = 0; mt < 4; ++mt)
            #pragma unroll
            for (int nt = 0; nt < NT; ++nt)
                acc[mt][nt] = __builtin_amdgcn_mfma_f32_16x16x32_bf16(ah[mt], bh[nt], acc[mt][nt], 0, 0, 0);
        #pragma unroll
        for (int mt = 0; mt < 4; ++mt)
            #pragma unroll
            for (int nt = 0; nt < NT; ++nt)
                acc[mt][nt] = __builtin_amdgcn_mfma_f32_16x16x32_bf16(ah[mt], bl[nt], acc[mt][nt], 0, 0, 0);
    }
    // k-tiles [MT8, KT8): full split — groups Ah·Wh, Al·Wh, Ah·Wl
    #pragma unroll 1
    for (int s = MT8; s < KT8; ++s) {
        int koff = s * 32;
        short8 ah[4], al[4];
        #pragma unroll
        for (int mt = 0; mt < 4; ++mt) {
            ah[mt] = *(const short8*)(A + aoff[mt] + koff);
            al[mt] = *(const short8*)(A + aoff[mt] + KT8 * 32 + koff);
        }
        short8 bh[NT], bl[NT];
        #pragma unroll
        for (int nt = 0; nt < NT; ++nt) {
            bh[nt] = *(const short8*)(Whi + (size_t)s * NC * 32 + nb[nt]);
            bl[nt] = *(const short8*)(Wlo + (size_t)s * NC * 32 + nb[nt]);
        }
        #pragma unroll
        for (int mt = 0; mt < 4; ++mt)
            #pragma unroll
            for (int nt = 0; nt < NT; ++nt)
                acc[mt][nt] = __builtin_amdgcn_mfma_f32_16x16x32_bf16(ah[mt], bh[nt], acc[mt][nt], 0, 0, 0);
        #pragma unroll
        for (int mt = 0; mt < 4; ++mt)
            #pragma unroll
            for (int nt = 0; nt < NT; ++nt)
                acc[mt][nt] = __builtin_amdgcn_mfma_f32_16x16x32_bf16(al[mt], bh[nt], acc[mt][nt], 0, 0, 0);
        #pragma unroll
        for (int mt = 0; mt < 4; ++mt)
            #pragma unroll
            for (int nt = 0; nt < NT; ++nt)
                acc[mt][nt] = __builtin_amdgcn_mfma_f32_16x16x32_bf16(ah[mt], bl[nt], acc[mt][nt], 0, 0, 0);
    }

    // Epilogue: two phases of 32 rows.  C/D layout: col = lane&15, row = quad*4 + reg.
    constexpr int CW = NC / 8;        // cols per epilogue thread (8 threads/row)
    int er = t >> 3, q = t & 7;
    int cb = q * CW;

    #pragma unroll
    for (int p = 0; p < 2; ++p) {
        if (p) __syncthreads();       // phase-0 readers done before overwrite
        #pragma unroll
        for (int mt2 = 0; mt2 < 2; ++mt2) {
            int mt = 2 * p + mt2;
            #pragma unroll
            for (int nt = 0; nt < NT; ++nt)
                #pragma unroll
                for (int r = 0; r < 4; ++r)
                    Cb[mt2 * 16 + kg * 4 + r][w * (NC / 4) + nt * 16 + l15] = acc[mt][nt][r];
        }
        __syncthreads();

        int gr = m0 + p * 32 + er;

        if (EPI == 0) {
            if (gr < n) {
                #pragma unroll
                for (int i = 0; i < CW / 4; ++i) {
                    int c = cb + 4 * i;
                    float4 v  = *(const float4*)&Cb[er][c];
                    float4 bi = *(const float4*)&bias[c];
                    float o0 = fmaxf(v.x + bi.x, 0.f), o1 = fmaxf(v.y + bi.y, 0.f);
                    float o2 = fmaxf(v.z + bi.z, 0.f), o3 = fmaxf(v.w + bi.w, 0.f);
                    unsigned short h0 = f2bf(o0), h1 = f2bf(o1), h2 = f2bf(o2), h3 = f2bf(o3);
                    ushort4 hv = make_ushort4(h0, h1, h2, h3);
                    ushort4 lv = make_ushort4(f2bf(o0 - bf2f(h0)), f2bf(o1 - bf2f(h1)),
                                              f2bf(o2 - bf2f(h2)), f2bf(o3 - bf2f(h3)));
                    *(ushort4*)(DstH + (size_t)gr * DSK + c) = hv;
                    *(ushort4*)(DstL + (size_t)gr * DSK + c) = lv;
                }
            }
        } else if (EPI == 1) {
            float s = 0.f, ss = 0.f;
            #pragma unroll
            for (int i = 0; i < CW / 4; ++i) {
                int c = cb + 4 * i;
                float4 v  = *(const float4*)&Cb[er][c];
                float4 bi = *(const float4*)&bias[c];
                float a0 = v.x + bi.x, a1 = v.y + bi.y, a2 = v.z + bi.z, a3 = v.w + bi.w;
                s  += a0 + a1 + a2 + a3;
                ss += a0 * a0 + a1 * a1 + a2 * a2 + a3 * a3;
            }
            s  += __shfl_xor(s, 1);  s  += __shfl_xor(s, 2);  s  += __shfl_xor(s, 4);
            ss += __shfl_xor(ss, 1); ss += __shfl_xor(ss, 2); ss += __shfl_xor(ss, 4);
            float mu  = s * (1.f / NC);
            float var = ss * (1.f / NC) - mu * mu;
            float rs  = rsqrtf(var + 1e-5f);
            if (gr < n) {
                #pragma unroll
                for (int i = 0; i < CW / 4; ++i) {
                    int c = cb + 4 * i;
                    float4 v  = *(const float4*)&Cb[er][c];
                    float4 bi = *(const float4*)&bias[c];
                    float4 gg = *(const float4*)&g[c];
                    float4 bb = *(const float4*)&be[c];
                    float r0 = fmaxf((v.x + bi.x - mu) * rs * gg.x + bb.x, 0.f);
                    float r1 = fmaxf((v.y + bi.y - mu) * rs * gg.y + bb.y, 0.f);
                    float r2 = fmaxf((v.z + bi.z - mu) * rs * gg.z + bb.z, 0.f);
                    float r3 = fmaxf((v.w + bi.w - mu) * rs * gg.w + bb.w, 0.f);
                    ushort4 rh = *(const ushort4*)(SrcH + (size_t)gr * SSK + c);
                    ushort4 rl = *(const ushort4*)(SrcL + (size_t)gr * SSK + c);
                    float o0 = bf2f(rh.x) + bf2f(rl.x) + 0.5f * r0;
                    float o1 = bf2f(rh.y) + bf2f(rl.y) + 0.5f * r1;
                    float o2 = bf2f(rh.z) + bf2f(rl.z) + 0.5f * r2;
                    float o3 = bf2f(rh.w) + bf2f(rl.w) + 0.5f * r3;
                    unsigned short h0 = f2bf(o0), h1 = f2bf(o1), h2 = f2bf(o2), h3 = f2bf(o3);
                    ushort4 hv = make_ushort4(h0, h1, h2, h3);
                    ushort4 lv = make_ushort4(f2bf(o0 - bf2f(h0)), f2bf(o1 - bf2f(h1)),
                                              f2bf(o2 - bf2f(h2)), f2bf(o3 - bf2f(h3)));
                    *(ushort4*)(DstH + (size_t)gr * DSK + c) = hv;
                    *(ushort4*)(DstL + (size_t)gr * DSK + c) = lv;
                }
            }
        } else {
            float s = 0.f;
            #pragma unroll
            for (int i = 0; i < CW / 4; ++i) {
                int c = cb + 4 * i;
                float4 v  = *(const float4*)&Cb[er][c];
                float4 bi = *(const float4*)&bias[c];
                float4 w2 = *(const float4*)&wh2[c];
                s += fmaxf(v.x + bi.x, 0.f) * w2.x + fmaxf(v.y + bi.y, 0.f) * w2.y
                   + fmaxf(v.z + bi.z, 0.f) * w2.z + fmaxf(v.w + bi.w, 0.f) * w2.w;
            }
            s += __shfl_xor(s, 1); s += __shfl_xor(s, 2); s += __shfl_xor(s, 4);
            if (q == 0 && gr < n) outp[gr] = s + bh2[0];
        }
    }
}

// ---------------- launcher ----------------
extern "C" void kernel_launch(void* const* d_in, const int* in_sizes, int n_in,
                              void* d_out, int out_size, void* d_ws, size_t ws_size,
                              hipStream_t stream)
{
    const float* xnum = (const float*)d_in[0];
    const int*   xcat = (const int*)d_in[1];
    const int*   eidx = (const int*)d_in[2];
    const float* e0   = (const float*)d_in[3];
    const float* e1   = (const float*)d_in[4];
    const float* e2   = (const float*)d_in[5];
    const float* e3   = (const float*)d_in[6];
    const float* w_in = (const float*)d_in[7];
    const float* b_in = (const float*)d_in[8];
    const float* w1l  = (const float*)d_in[9];
    const float* b1l  = (const float*)d_in[10];
    const float* w1r  = (const float*)d_in[11];
    const float* w2l  = (const float*)d_in[12];
    const float* b2l  = (const float*)d_in[13];
    const float* w2r  = (const float*)d_in[14];
    const float* g1   = (const float*)d_in[15];
    const float* be1  = (const float*)d_in[16];
    const float* g2   = (const float*)d_in[17];
    const float* be2  = (const float*)d_in[18];
    const float* wh1  = (const float*)d_in[19];
    const float* bh1  = (const float*)d_in[20];
    const float* wh2  = (const float*)d_in[21];
    const float* bh2  = (const float*)d_in[22];

    int n = in_sizes[0] / 32;
    int ecount = in_sizes[2] / 2;
    const int* esrc = eidx;
    const int* edst = eidx + ecount;

    char* ws = (char*)d_ws;
    size_t off = 0;
    auto alloc = [&](size_t bytes) -> void* {
        void* p = ws + off;
        off += (bytes + 255) & ~(size_t)255;
        return p;
    };
    // Region R0: A1 (n x 512 pairs) ; A3 (n x 256) aliases it (A1 dead after conv1).
    unsigned short* A1 = (unsigned short*)alloc((size_t)n * 512 * 2);
    unsigned short* A3 = A1;
    // Region R1: A2 (n x 512) ; A0 (n x 192) aliases it (A0 dead before conv1 epilogue writes A2).
    unsigned short* A2 = (unsigned short*)alloc((size_t)n * 512 * 2);
    unsigned short* A0 = A2;
    // Weight fragment buffers
    unsigned short* w0h = (unsigned short*)alloc((size_t)96 * 128 * 2);
    unsigned short* w0l = (unsigned short*)alloc((size_t)96 * 128 * 2);
    unsigned short* w1h = (unsigned short*)alloc((size_t)256 * 128 * 2);
    unsigned short* w1lo= (unsigned short*)alloc((size_t)256 * 128 * 2);
    unsigned short* w2h = (unsigned short*)alloc((size_t)256 * 128 * 2);
    unsigned short* w2lo= (unsigned short*)alloc((size_t)256 * 128 * 2);
    unsigned short* whh = (unsigned short*)alloc((size_t)128 * 64 * 2);
    unsigned short* whl = (unsigned short*)alloc((size_t)128 * 64 * 2);
    // CSR
    int* cnt     = (int*)alloc((size_t)n * 4);
    int* row_ptr = (int*)alloc((size_t)(n + 1) * 4);
    int* rank    = (int*)alloc((size_t)ecount * 4);
    int* col     = (int*)alloc((size_t)ecount * 4);
    int nb1 = (n + 4095) / 4096;
    int* bsum    = (int*)alloc((size_t)nb1 * 4);
    (void)ws_size; (void)n_in; (void)out_size;

    int gemmBlocks = (n + 63) / 64;
    int gridE = 2048;
    int aggBlocks = (n + 3) / 4;

    // weight prep
    k_prepw<<<(96 * 128 + 255) / 256, 256, 0, stream>>>(w_in, 71, nullptr, 0, 96, 128, w0h, w0l);
    k_prepw<<<(256 * 128 + 255) / 256, 256, 0, stream>>>(w1l, 128, w1r, 128, 256, 128, w1h, w1lo);
    k_prepw<<<(256 * 128 + 255) / 256, 256, 0, stream>>>(w2l, 128, w2r, 128, 256, 128, w2h, w2lo);
    k_prepw<<<(128 * 64 + 255) / 256, 256, 0, stream>>>(wh1, 128, nullptr, 0, 128, 64, whh, whl);

    // input features -> A0
    k_stack0<<<((size_t)n * 6 + 255) / 256, 256, 0, stream>>>(xnum, xcat, e0, e1, e2, e3, A0, n);

    // CSR build (by dst): rank -> scan -> place
    hipMemsetAsync(cnt, 0, (size_t)n * 4, stream);
    k_rank<<<gridE, 256, 0, stream>>>(edst, cnt, rank, ecount);
    k_scan1<<<nb1, 1024, 0, stream>>>(cnt, row_ptr, bsum, n);
    k_scan2<<<1, 64, 0, stream>>>(bsum, nb1);
    k_scan3<<<(n + 255) / 256, 256, 0, stream>>>(row_ptr, bsum, n, ecount);
    k_place<<<gridE, 256, 0, stream>>>(esrc, edst, rank, row_ptr, col, ecount, n);

    // input MLP: A0[192] @ W0 -> x0 pairs into A1 x-slots (hi@128, lo@384)
    k_gemm<128, 3, 0, 0><<<gemmBlocks, 256, 0, stream>>>(
        A0, 192, w0h, w0l, b_in,
        nullptr, nullptr, nullptr, nullptr, 0,
        A1 + 128, A1 + 384, 512,
        nullptr, nullptr, nullptr, n);

    // conv1: mean_hi of x0 -> A1 mean-slots; GEMM A1[512] @ [w1l;w1r] -> x1 pairs -> A2 x-slots
    k_agg<<<aggBlocks, 256, 0, stream>>>(A1 + 128, A1, 512, row_ptr, col, n);
    k_gemm<128, 8, 4, 1><<<gemmBlocks, 256, 0, stream>>>(
        A1, 512, w1h, w1lo, b1l,
        g1, be1, A1 + 128, A1 + 384, 512,
        A2 + 128, A2 + 384, 512,
        nullptr, nullptr, nullptr, n);

    // conv2: mean_hi of x1 -> A2 mean-slots; GEMM A2[512] -> x2 pairs -> A3 (hi@0, lo@128)
    k_agg<<<aggBlocks, 256, 0, stream>>>(A2 + 128, A2, 512, row_ptr, col, n);
    k_gemm<128, 8, 4, 1><<<gemmBlocks, 256, 0, stream>>>(
        A2, 512, w2h, w2lo, b2l,
        g2, be2, A2 + 128, A2 + 384, 512,
        A3, A3 + 128, 256,
        nullptr, nullptr, nullptr, n);

    // head: A3[256] @ wh1 -> relu -> ·wh2 + bh2 -> out
    k_gemm<64, 4, 0, 2><<<gemmBlocks, 256, 0, stream>>>(
        A3, 256, whh, whl, bh1,
        nullptr, nullptr, nullptr, nullptr, 0,
        nullptr, nullptr, 0,
        wh2, bh2, (float*)d_out, n);
}

// Round 8
// 577.914 us; speedup vs baseline: 1.7189x; 1.1286x over previous
//
#include <hip/hip_runtime.h>

#define HID 128

typedef __attribute__((ext_vector_type(8))) short short8;
typedef __attribute__((ext_vector_type(4))) float f32x4;

__device__ __forceinline__ float bf2f(unsigned short u) {
    unsigned int x = ((unsigned int)u) << 16;
    return __builtin_bit_cast(float, x);
}
__device__ __forceinline__ unsigned short f2bf(float f) {
    unsigned int u = __builtin_bit_cast(unsigned int, f);
    u += 0x7fffu + ((u >> 16) & 1u);
    return (unsigned short)(u >> 16);
}

// ---------------- weight prep: fp32 [K,N] (optionally two stacked sources) ->
// fragment layout hi/lo: elem (k,n) at ((k/32)*N + n)*32 + k%32 ----------------
__global__ __launch_bounds__(256) void k_prepw(const float* __restrict__ s1, int k1,
    const float* __restrict__ s2, int k2, int Kp, int N,
    unsigned short* __restrict__ whi, unsigned short* __restrict__ wlo)
{
    int i = blockIdx.x * 256 + threadIdx.x;
    if (i >= Kp * N) return;
    int k = i / N, nn = i - k * N;
    float v = 0.f;
    if (k < k1) v = s1[(size_t)k * N + nn];
    else if (k < k1 + k2) v = s2[(size_t)(k - k1) * N + nn];
    unsigned short h = f2bf(v);
    unsigned short l = f2bf(v - bf2f(h));
    size_t o = ((size_t)(k >> 5) * N + nn) * 32 + (k & 31);
    whi[o] = h; wlo[o] = l;
}

// ---------------- input feature prestack: [xnum | emb0..3 | pad] -> bf16 hi/lo pairs,
// A0 row-major [n][192] = [hi(96) | lo(96)].  6 chunks of 16 cols per row. ----------------
__global__ __launch_bounds__(256) void k_stack0(
    const float* __restrict__ xnum, const int* __restrict__ xcat,
    const float* __restrict__ e0, const float* __restrict__ e1,
    const float* __restrict__ e2, const float* __restrict__ e3,
    unsigned short* __restrict__ A0, int n)
{
    int g = blockIdx.x * 256 + threadIdx.x;
    int r = g / 6, c = g - r * 6;              // 6 chunks of 16 cols (96 features)
    if (r >= n) return;
    int4 cc = ((const int4*)xcat)[r];
    float v[16];
    int base = c * 16;
    #pragma unroll
    for (int j = 0; j < 16; ++j) {
        int col = base + j;
        float val;
        if      (col < 32) val = xnum[(size_t)r * 32 + col];
        else if (col < 42) val = e0[(size_t)cc.x * 10 + (col - 32)];
        else if (col < 48) val = e1[(size_t)cc.y * 6  + (col - 42)];
        else if (col < 53) val = e2[(size_t)cc.z * 5  + (col - 48)];
        else if (col < 71) val = e3[(size_t)cc.w * 18 + (col - 53)];
        else               val = 0.f;
        v[j] = val;
    }
    unsigned int ph[8], pl[8];
    #pragma unroll
    for (int j = 0; j < 8; ++j) {
        unsigned short h0 = f2bf(v[2*j]),   h1 = f2bf(v[2*j+1]);
        unsigned short l0 = f2bf(v[2*j]   - bf2f(h0));
        unsigned short l1 = f2bf(v[2*j+1] - bf2f(h1));
        ph[j] = (unsigned int)h0 | ((unsigned int)h1 << 16);
        pl[j] = (unsigned int)l0 | ((unsigned int)l1 << 16);
    }
    unsigned int* dh = (unsigned int*)(A0 + (size_t)r * 192 + base);
    unsigned int* dl = (unsigned int*)(A0 + (size_t)r * 192 + 96 + base);
    uint4 a; a.x = ph[0]; a.y = ph[1]; a.z = ph[2]; a.w = ph[3];
    uint4 b; b.x = ph[4]; b.y = ph[5]; b.z = ph[6]; b.w = ph[7];
    ((uint4*)dh)[0] = a; ((uint4*)dh)[1] = b;
    a.x = pl[0]; a.y = pl[1]; a.z = pl[2]; a.w = pl[3];
    b.x = pl[4]; b.y = pl[5]; b.z = pl[6]; b.w = pl[7];
    ((uint4*)dl)[0] = a; ((uint4*)dl)[1] = b;
}

// ---------------- CSR build: rank (atomics paid once) + scan + atomic-free place ----------------
__global__ __launch_bounds__(256) void k_rank(const int* __restrict__ dst,
    int* __restrict__ cnt, int* __restrict__ rank, int ecount)
{
    int i = blockIdx.x * blockDim.x + threadIdx.x;
    int stride = gridDim.x * blockDim.x;
    for (; i < ecount; i += stride)
        rank[i] = atomicAdd(&cnt[dst[i]], 1);
}

__global__ __launch_bounds__(1024) void k_scan1(const int* __restrict__ cnt,
    int* __restrict__ excl, int* __restrict__ bsum, int n)
{
    __shared__ int sm[1024];
    int t = threadIdx.x;
    int base = blockIdx.x * 4096 + t * 4;
    int v0 = (base + 0 < n) ? cnt[base + 0] : 0;
    int v1 = (base + 1 < n) ? cnt[base + 1] : 0;
    int v2 = (base + 2 < n) ? cnt[base + 2] : 0;
    int v3 = (base + 3 < n) ? cnt[base + 3] : 0;
    int s = v0 + v1 + v2 + v3;
    sm[t] = s;
    __syncthreads();
    for (int offd = 1; offd < 1024; offd <<= 1) {
        int tv = (t >= offd) ? sm[t - offd] : 0;
        __syncthreads();
        sm[t] += tv;
        __syncthreads();
    }
    int incl = sm[t];
    int ex = incl - s;
    if (t == 1023) bsum[blockIdx.x] = incl;
    if (base + 0 < n) excl[base + 0] = ex; ex += v0;
    if (base + 1 < n) excl[base + 1] = ex; ex += v1;
    if (base + 2 < n) excl[base + 2] = ex; ex += v2;
    if (base + 3 < n) excl[base + 3] = ex;
}

__global__ void k_scan2(int* __restrict__ bsum, int nb)
{
    if (threadIdx.x == 0 && blockIdx.x == 0) {
        int run = 0;
        for (int i = 0; i < nb; ++i) { int t = bsum[i]; bsum[i] = run; run += t; }
    }
}

__global__ __launch_bounds__(256) void k_scan3(int* __restrict__ row_ptr,
    const int* __restrict__ bsum, int n, int ecount)
{
    int i = blockIdx.x * 256 + threadIdx.x;
    if (i < n)
        row_ptr[i] = row_ptr[i] + bsum[i >> 12];
    if (i == 0) row_ptr[n] = ecount;
}

// node-range-grouped placement: group g = blockIdx&7 handles nodes [g*per8,(g+1)*per8)
// -> each group's col region (~E/8*4B ~ 800 KB) stays L2-resident, written back once.
__global__ __launch_bounds__(256) void k_place(const int* __restrict__ src,
    const int* __restrict__ dst, const int* __restrict__ rank,
    const int* __restrict__ row_ptr, int* __restrict__ col, int ecount, int n)
{
    int g  = blockIdx.x & 7;
    int per8 = (n + 7) >> 3;
    int lo = g * per8;
    int hi = lo + per8 < n ? lo + per8 : n;
    int bl = blockIdx.x >> 3;
    int nb = gridDim.x >> 3;
    int i = bl * blockDim.x + threadIdx.x;
    int stride = nb * blockDim.x;
    for (; i < ecount; i += stride) {
        int d = dst[i];
        if (d >= lo && d < hi)
            col[row_ptr[d] + rank[i]] = src[i];
    }
}

// ---------------- mean aggregation, hi-only: one wave per node, 2 edges/wave, unroll 4 ----------------
// lanes 0-31 = even edges, lanes 32-63 = odd edges; each lane covers 4 cols (uint2 = 8 B).
// 4 pair-steps in flight per body -> 8 row-gathers outstanding (1 KB) vs 1 before.
__global__ __launch_bounds__(256) void k_agg(
    const unsigned short* __restrict__ xh, unsigned short* __restrict__ mh, int SK,
    const int* __restrict__ row_ptr, const int* __restrict__ col, int n)
{
    int lane = threadIdx.x & 63;
    int half = lane >> 5;
    int l32  = lane & 31;
    int node = blockIdx.x * 4 + (threadIdx.x >> 6);
    if (node >= n) return;
    node = __builtin_amdgcn_readfirstlane(node);
    int s = row_ptr[node], e = row_ptr[node + 1];
    int deg = e - s;
    float a0 = 0.f, a1 = 0.f, a2 = 0.f, a3 = 0.f;
    size_t cOff = (size_t)l32 * 4;        // 4 bf16 cols per lane

    auto accum = [&](uint2 r) {
        a0 += __builtin_bit_cast(float, r.x << 16);
        a1 += __builtin_bit_cast(float, r.x & 0xffff0000u);
        a2 += __builtin_bit_cast(float, r.y << 16);
        a3 += __builtin_bit_cast(float, r.y & 0xffff0000u);
    };

    int p = s + half;
    for (; p + 6 < e; p += 8) {           // 4 pair-steps: edges p, p+2, p+4, p+6 (this half)
        int sc0 = col[p];
        int sc1 = col[p + 2];
        int sc2 = col[p + 4];
        int sc3 = col[p + 6];
        uint2 r0 = *(const uint2*)(xh + (size_t)sc0 * SK + cOff);
        uint2 r1 = *(const uint2*)(xh + (size_t)sc1 * SK + cOff);
        uint2 r2 = *(const uint2*)(xh + (size_t)sc2 * SK + cOff);
        uint2 r3 = *(const uint2*)(xh + (size_t)sc3 * SK + cOff);
        accum(r0); accum(r1); accum(r2); accum(r3);
    }
    for (; p < e; p += 2) {
        int sc = col[p];
        accum(*(const uint2*)(xh + (size_t)sc * SK + cOff));
    }

    a0 += __shfl_xor(a0, 32);
    a1 += __shfl_xor(a1, 32);
    a2 += __shfl_xor(a2, 32);
    a3 += __shfl_xor(a3, 32);

    if (half == 0) {
        float inv = 1.f / (float)(deg > 1 ? deg : 1);
        a0 *= inv; a1 *= inv; a2 *= inv; a3 *= inv;
        uint2 o;
        o.x = (unsigned int)f2bf(a0) | ((unsigned int)f2bf(a1) << 16);
        o.y = (unsigned int)f2bf(a2) | ((unsigned int)f2bf(a3) << 16);
        *(uint2*)(mh + (size_t)node * SK + cOff) = o;
    }
}

// ---------------- generic split-bf16 MFMA GEMM, M-tile=64, block=256 ----------------
// A' row-major [m][SK], SK = 2*KT8*32 = [hi-half | lo-half].
// First MT8 k-tiles have no valid lo (mean stored hi-only): skip the Al·Wh group there.
// Merged K-loop (#pragma unroll 1): per k-tile load fragments once, issue MFMA groups.
// Epilogue in 2 phases of 32 rows (LDS 16.9 KB), 8 threads/row.
// EPI 0: out = relu(C+bias) -> pair store.  EPI 1: LN+relu, out = res + 0.5*r -> pair store.
// EPI 2: head: s = relu(C+bias)·wh2 + bh2 -> outp.
template<int NC, int KT8, int MT8, int EPI>
__global__ __launch_bounds__(256) void k_gemm(
    const unsigned short* __restrict__ A, int SK,
    const unsigned short* __restrict__ Whi, const unsigned short* __restrict__ Wlo,
    const float* __restrict__ bias,
    const float* __restrict__ g, const float* __restrict__ be,
    const unsigned short* __restrict__ SrcH, const unsigned short* __restrict__ SrcL, int SSK,
    unsigned short* __restrict__ DstH, unsigned short* __restrict__ DstL, int DSK,
    const float* __restrict__ wh2, const float* __restrict__ bh2, float* __restrict__ outp,
    int n)
{
    constexpr int NT = NC / 64;       // n-16-tiles per wave
    __shared__ float Cb[32][NC + 4];
    int t = threadIdx.x;
    int lane = t & 63, w = t >> 6;
    int l15 = lane & 15, kg = lane >> 4;
    int m0 = blockIdx.x * 64;

    size_t aoff[4];
    #pragma unroll
    for (int mt = 0; mt < 4; ++mt) {
        int r = m0 + mt * 16 + l15;
        r = r < n ? r : n - 1;
        aoff[mt] = (size_t)r * SK + kg * 8;
    }
    size_t nb[NT];
    #pragma unroll
    for (int nt = 0; nt < NT; ++nt)
        nb[nt] = (size_t)(w * (NC / 4) + nt * 16 + l15) * 32 + kg * 8;

    f32x4 acc[4][NT];
    #pragma unroll
    for (int mt = 0; mt < 4; ++mt)
        #pragma unroll
        for (int nt = 0; nt < NT; ++nt)
            acc[mt][nt] = (f32x4)(0.f);

    // k-tiles [0, MT8): hi-only A (mean region) — groups Ah·Wh, Ah·Wl
    #pragma unroll 1
    for (int s = 0; s < MT8; ++s) {
        int koff = s * 32;
        short8 ah[4];
        #pragma unroll
        for (int mt = 0; mt < 4; ++mt)
            ah[mt] = *(const short8*)(A + aoff[mt] + koff);
        short8 bh[NT], bl[NT];
        #pragma unroll
        for (int nt = 0; nt < NT; ++nt) {
            bh[nt] = *(const short8*)(Whi + (size_t)s * NC * 32 + nb[nt]);
            bl[nt] = *(const short8*)(Wlo + (size_t)s * NC * 32 + nb[nt]);
        }
        #pragma unroll
        for (int mt = 0; mt < 4; ++mt)
            #pragma unroll
            for (int nt = 0; nt < NT; ++nt)
                acc[mt][nt] = __builtin_amdgcn_mfma_f32_16x16x32_bf16(ah[mt], bh[nt], acc[mt][nt], 0, 0, 0);
        #pragma unroll
        for (int mt = 0; mt < 4; ++mt)
            #pragma unroll
            for (int nt = 0; nt < NT; ++nt)
                acc[mt][nt] = __builtin_amdgcn_mfma_f32_16x16x32_bf16(ah[mt], bl[nt], acc[mt][nt], 0, 0, 0);
    }
    // k-tiles [MT8, KT8): full split — groups Ah·Wh, Al·Wh, Ah·Wl
    #pragma unroll 1
    for (int s = MT8; s < KT8; ++s) {
        int koff = s * 32;
        short8 ah[4], al[4];
        #pragma unroll
        for (int mt = 0; mt < 4; ++mt) {
            ah[mt] = *(const short8*)(A + aoff[mt] + koff);
            al[mt] = *(const short8*)(A + aoff[mt] + KT8 * 32 + koff);
        }
        short8 bh[NT], bl[NT];
        #pragma unroll
        for (int nt = 0; nt < NT; ++nt) {
            bh[nt] = *(const short8*)(Whi + (size_t)s * NC * 32 + nb[nt]);
            bl[nt] = *(const short8*)(Wlo + (size_t)s * NC * 32 + nb[nt]);
        }
        #pragma unroll
        for (int mt = 0; mt < 4; ++mt)
            #pragma unroll
            for (int nt = 0; nt < NT; ++nt)
                acc[mt][nt] = __builtin_amdgcn_mfma_f32_16x16x32_bf16(ah[mt], bh[nt], acc[mt][nt], 0, 0, 0);
        #pragma unroll
        for (int mt = 0; mt < 4; ++mt)
            #pragma unroll
            for (int nt = 0; nt < NT; ++nt)
                acc[mt][nt] = __builtin_amdgcn_mfma_f32_16x16x32_bf16(al[mt], bh[nt], acc[mt][nt], 0, 0, 0);
        #pragma unroll
        for (int mt = 0; mt < 4; ++mt)
            #pragma unroll
            for (int nt = 0; nt < NT; ++nt)
                acc[mt][nt] = __builtin_amdgcn_mfma_f32_16x16x32_bf16(ah[mt], bl[nt], acc[mt][nt], 0, 0, 0);
    }

    // Epilogue: two phases of 32 rows.  C/D layout: col = lane&15, row = quad*4 + reg.
    constexpr int CW = NC / 8;        // cols per epilogue thread (8 threads/row)
    int er = t >> 3, q = t & 7;
    int cb = q * CW;

    #pragma unroll
    for (int p = 0; p < 2; ++p) {
        if (p) __syncthreads();       // phase-0 readers done before overwrite
        #pragma unroll
        for (int mt2 = 0; mt2 < 2; ++mt2) {
            int mt = 2 * p + mt2;
            #pragma unroll
            for (int nt = 0; nt < NT; ++nt)
                #pragma unroll
                for (int r = 0; r < 4; ++r)
                    Cb[mt2 * 16 + kg * 4 + r][w * (NC / 4) + nt * 16 + l15] = acc[mt][nt][r];
        }
        __syncthreads();

        int gr = m0 + p * 32 + er;

        if (EPI == 0) {
            if (gr < n) {
                #pragma unroll
                for (int i = 0; i < CW / 4; ++i) {
                    int c = cb + 4 * i;
                    float4 v  = *(const float4*)&Cb[er][c];
                    float4 bi = *(const float4*)&bias[c];
                    float o0 = fmaxf(v.x + bi.x, 0.f), o1 = fmaxf(v.y + bi.y, 0.f);
                    float o2 = fmaxf(v.z + bi.z, 0.f), o3 = fmaxf(v.w + bi.w, 0.f);
                    unsigned short h0 = f2bf(o0), h1 = f2bf(o1), h2 = f2bf(o2), h3 = f2bf(o3);
                    ushort4 hv = make_ushort4(h0, h1, h2, h3);
                    ushort4 lv = make_ushort4(f2bf(o0 - bf2f(h0)), f2bf(o1 - bf2f(h1)),
                                              f2bf(o2 - bf2f(h2)), f2bf(o3 - bf2f(h3)));
                    *(ushort4*)(DstH + (size_t)gr * DSK + c) = hv;
                    *(ushort4*)(DstL + (size_t)gr * DSK + c) = lv;
                }
            }
        } else if (EPI == 1) {
            float s = 0.f, ss = 0.f;
            #pragma unroll
            for (int i = 0; i < CW / 4; ++i) {
                int c = cb + 4 * i;
                float4 v  = *(const float4*)&Cb[er][c];
                float4 bi = *(const float4*)&bias[c];
                float a0 = v.x + bi.x, a1 = v.y + bi.y, a2 = v.z + bi.z, a3 = v.w + bi.w;
                s  += a0 + a1 + a2 + a3;
                ss += a0 * a0 + a1 * a1 + a2 * a2 + a3 * a3;
            }
            s  += __shfl_xor(s, 1);  s  += __shfl_xor(s, 2);  s  += __shfl_xor(s, 4);
            ss += __shfl_xor(ss, 1); ss += __shfl_xor(ss, 2); ss += __shfl_xor(ss, 4);
            float mu  = s * (1.f / NC);
            float var = ss * (1.f / NC) - mu * mu;
            float rs  = rsqrtf(var + 1e-5f);
            if (gr < n) {
                #pragma unroll
                for (int i = 0; i < CW / 4; ++i) {
                    int c = cb + 4 * i;
                    float4 v  = *(const float4*)&Cb[er][c];
                    float4 bi = *(const float4*)&bias[c];
                    float4 gg = *(const float4*)&g[c];
                    float4 bb = *(const float4*)&be[c];
                    float r0 = fmaxf((v.x + bi.x - mu) * rs * gg.x + bb.x, 0.f);
                    float r1 = fmaxf((v.y + bi.y - mu) * rs * gg.y + bb.y, 0.f);
                    float r2 = fmaxf((v.z + bi.z - mu) * rs * gg.z + bb.z, 0.f);
                    float r3 = fmaxf((v.w + bi.w - mu) * rs * gg.w + bb.w, 0.f);
                    ushort4 rh = *(const ushort4*)(SrcH + (size_t)gr * SSK + c);
                    ushort4 rl = *(const ushort4*)(SrcL + (size_t)gr * SSK + c);
                    float o0 = bf2f(rh.x) + bf2f(rl.x) + 0.5f * r0;
                    float o1 = bf2f(rh.y) + bf2f(rl.y) + 0.5f * r1;
                    float o2 = bf2f(rh.z) + bf2f(rl.z) + 0.5f * r2;
                    float o3 = bf2f(rh.w) + bf2f(rl.w) + 0.5f * r3;
                    unsigned short h0 = f2bf(o0), h1 = f2bf(o1), h2 = f2bf(o2), h3 = f2bf(o3);
                    ushort4 hv = make_ushort4(h0, h1, h2, h3);
                    ushort4 lv = make_ushort4(f2bf(o0 - bf2f(h0)), f2bf(o1 - bf2f(h1)),
                                              f2bf(o2 - bf2f(h2)), f2bf(o3 - bf2f(h3)));
                    *(ushort4*)(DstH + (size_t)gr * DSK + c) = hv;
                    *(ushort4*)(DstL + (size_t)gr * DSK + c) = lv;
                }
            }
        } else {
            float s = 0.f;
            #pragma unroll
            for (int i = 0; i < CW / 4; ++i) {
                int c = cb + 4 * i;
                float4 v  = *(const float4*)&Cb[er][c];
                float4 bi = *(const float4*)&bias[c];
                float4 w2 = *(const float4*)&wh2[c];
                s += fmaxf(v.x + bi.x, 0.f) * w2.x + fmaxf(v.y + bi.y, 0.f) * w2.y
                   + fmaxf(v.z + bi.z, 0.f) * w2.z + fmaxf(v.w + bi.w, 0.f) * w2.w;
            }
            s += __shfl_xor(s, 1); s += __shfl_xor(s, 2); s += __shfl_xor(s, 4);
            if (q == 0 && gr < n) outp[gr] = s + bh2[0];
        }
    }
}

// ---------------- launcher ----------------
extern "C" void kernel_launch(void* const* d_in, const int* in_sizes, int n_in,
                              void* d_out, int out_size, void* d_ws, size_t ws_size,
                              hipStream_t stream)
{
    const float* xnum = (const float*)d_in[0];
    const int*   xcat = (const int*)d_in[1];
    const int*   eidx = (const int*)d_in[2];
    const float* e0   = (const float*)d_in[3];
    const float* e1   = (const float*)d_in[4];
    const float* e2   = (const float*)d_in[5];
    const float* e3   = (const float*)d_in[6];
    const float* w_in = (const float*)d_in[7];
    const float* b_in = (const float*)d_in[8];
    const float* w1l  = (const float*)d_in[9];
    const float* b1l  = (const float*)d_in[10];
    const float* w1r  = (const float*)d_in[11];
    const float* w2l  = (const float*)d_in[12];
    const float* b2l  = (const float*)d_in[13];
    const float* w2r  = (const float*)d_in[14];
    const float* g1   = (const float*)d_in[15];
    const float* be1  = (const float*)d_in[16];
    const float* g2   = (const float*)d_in[17];
    const float* be2  = (const float*)d_in[18];
    const float* wh1  = (const float*)d_in[19];
    const float* bh1  = (const float*)d_in[20];
    const float* wh2  = (const float*)d_in[21];
    const float* bh2  = (const float*)d_in[22];

    int n = in_sizes[0] / 32;
    int ecount = in_sizes[2] / 2;
    const int* esrc = eidx;
    const int* edst = eidx + ecount;

    char* ws = (char*)d_ws;
    size_t off = 0;
    auto alloc = [&](size_t bytes) -> void* {
        void* p = ws + off;
        off += (bytes + 255) & ~(size_t)255;
        return p;
    };
    // Region R0: A1 (n x 512 pairs) ; A3 (n x 256) aliases it (A1 dead after conv1).
    unsigned short* A1 = (unsigned short*)alloc((size_t)n * 512 * 2);
    unsigned short* A3 = A1;
    // Region R1: A2 (n x 512) ; A0 (n x 192) aliases it (A0 dead before conv1 epilogue writes A2).
    unsigned short* A2 = (unsigned short*)alloc((size_t)n * 512 * 2);
    unsigned short* A0 = A2;
    // Weight fragment buffers
    unsigned short* w0h = (unsigned short*)alloc((size_t)96 * 128 * 2);
    unsigned short* w0l = (unsigned short*)alloc((size_t)96 * 128 * 2);
    unsigned short* w1h = (unsigned short*)alloc((size_t)256 * 128 * 2);
    unsigned short* w1lo= (unsigned short*)alloc((size_t)256 * 128 * 2);
    unsigned short* w2h = (unsigned short*)alloc((size_t)256 * 128 * 2);
    unsigned short* w2lo= (unsigned short*)alloc((size_t)256 * 128 * 2);
    unsigned short* whh = (unsigned short*)alloc((size_t)128 * 64 * 2);
    unsigned short* whl = (unsigned short*)alloc((size_t)128 * 64 * 2);
    // CSR
    int* cnt     = (int*)alloc((size_t)n * 4);
    int* row_ptr = (int*)alloc((size_t)(n + 1) * 4);
    int* rank    = (int*)alloc((size_t)ecount * 4);
    int* col     = (int*)alloc((size_t)ecount * 4);
    int nb1 = (n + 4095) / 4096;
    int* bsum    = (int*)alloc((size_t)nb1 * 4);
    (void)ws_size; (void)n_in; (void)out_size;

    int gemmBlocks = (n + 63) / 64;
    int gridE = 2048;
    int aggBlocks = (n + 3) / 4;

    // weight prep
    k_prepw<<<(96 * 128 + 255) / 256, 256, 0, stream>>>(w_in, 71, nullptr, 0, 96, 128, w0h, w0l);
    k_prepw<<<(256 * 128 + 255) / 256, 256, 0, stream>>>(w1l, 128, w1r, 128, 256, 128, w1h, w1lo);
    k_prepw<<<(256 * 128 + 255) / 256, 256, 0, stream>>>(w2l, 128, w2r, 128, 256, 128, w2h, w2lo);
    k_prepw<<<(128 * 64 + 255) / 256, 256, 0, stream>>>(wh1, 128, nullptr, 0, 128, 64, whh, whl);

    // input features -> A0
    k_stack0<<<((size_t)n * 6 + 255) / 256, 256, 0, stream>>>(xnum, xcat, e0, e1, e2, e3, A0, n);

    // CSR build (by dst): rank -> scan -> place
    hipMemsetAsync(cnt, 0, (size_t)n * 4, stream);
    k_rank<<<gridE, 256, 0, stream>>>(edst, cnt, rank, ecount);
    k_scan1<<<nb1, 1024, 0, stream>>>(cnt, row_ptr, bsum, n);
    k_scan2<<<1, 64, 0, stream>>>(bsum, nb1);
    k_scan3<<<(n + 255) / 256, 256, 0, stream>>>(row_ptr, bsum, n, ecount);
    k_place<<<gridE, 256, 0, stream>>>(esrc, edst, rank, row_ptr, col, ecount, n);

    // input MLP: A0[192] @ W0 -> x0 pairs into A1 x-slots (hi@128, lo@384)
    k_gemm<128, 3, 0, 0><<<gemmBlocks, 256, 0, stream>>>(
        A0, 192, w0h, w0l, b_in,
        nullptr, nullptr, nullptr, nullptr, 0,
        A1 + 128, A1 + 384, 512,
        nullptr, nullptr, nullptr, n);

    // conv1: mean_hi of x0 -> A1 mean-slots; GEMM A1[512] @ [w1l;w1r] -> x1 pairs -> A2 x-slots
    k_agg<<<aggBlocks, 256, 0, stream>>>(A1 + 128, A1, 512, row_ptr, col, n);
    k_gemm<128, 8, 4, 1><<<gemmBlocks, 256, 0, stream>>>(
        A1, 512, w1h, w1lo, b1l,
        g1, be1, A1 + 128, A1 + 384, 512,
        A2 + 128, A2 + 384, 512,
        nullptr, nullptr, nullptr, n);

    // conv2: mean_hi of x1 -> A2 mean-slots; GEMM A2[512] -> x2 pairs -> A3 (hi@0, lo@128)
    k_agg<<<aggBlocks, 256, 0, stream>>>(A2 + 128, A2, 512, row_ptr, col, n);
    k_gemm<128, 8, 4, 1><<<gemmBlocks, 256, 0, stream>>>(
        A2, 512, w2h, w2lo, b2l,
        g2, be2, A2 + 128, A2 + 384, 512,
        A3, A3 + 128, 256,
        nullptr, nullptr, nullptr, n);

    // head: A3[256] @ wh1 -> relu -> ·wh2 + bh2 -> out
    k_gemm<64, 4, 0, 2><<<gemmBlocks, 256, 0, stream>>>(
        A3, 256, whh, whl, bh1,
        nullptr, nullptr, nullptr, nullptr, 0,
        nullptr, nullptr, 0,
        wh2, bh2, (float*)d_out, n);
}

// Round 9
// 512.205 us; speedup vs baseline: 1.9394x; 1.1283x over previous
//
#include <hip/hip_runtime.h>

#define HID 128

typedef __attribute__((ext_vector_type(8))) short short8;
typedef __attribute__((ext_vector_type(4))) float f32x4;

__device__ __forceinline__ float bf2f(unsigned short u) {
    unsigned int x = ((unsigned int)u) << 16;
    return __builtin_bit_cast(float, x);
}
__device__ __forceinline__ unsigned short f2bf(float f) {
    unsigned int u = __builtin_bit_cast(unsigned int, f);
    u += 0x7fffu + ((u >> 16) & 1u);
    return (unsigned short)(u >> 16);
}

// ---------------- weight prep: fp32 [K,N] (optionally two stacked sources) ->
// fragment layout hi/lo: elem (k,n) at ((k/32)*N + n)*32 + k%32 ----------------
// Weights KEEP the hi/lo split (removes systematic quantization bias; B loads are L2-hot).
__global__ __launch_bounds__(256) void k_prepw(const float* __restrict__ s1, int k1,
    const float* __restrict__ s2, int k2, int Kp, int N,
    unsigned short* __restrict__ whi, unsigned short* __restrict__ wlo)
{
    int i = blockIdx.x * 256 + threadIdx.x;
    if (i >= Kp * N) return;
    int k = i / N, nn = i - k * N;
    float v = 0.f;
    if (k < k1) v = s1[(size_t)k * N + nn];
    else if (k < k1 + k2) v = s2[(size_t)(k - k1) * N + nn];
    unsigned short h = f2bf(v);
    unsigned short l = f2bf(v - bf2f(h));
    size_t o = ((size_t)(k >> 5) * N + nn) * 32 + (k & 31);
    whi[o] = h; wlo[o] = l;
}

// ---------------- input feature prestack: [xnum | emb0..3 | pad] -> bf16 (hi only),
// A0 row-major [n][96].  6 chunks of 16 cols per row. ----------------
__global__ __launch_bounds__(256) void k_stack0(
    const float* __restrict__ xnum, const int* __restrict__ xcat,
    const float* __restrict__ e0, const float* __restrict__ e1,
    const float* __restrict__ e2, const float* __restrict__ e3,
    unsigned short* __restrict__ A0, int n)
{
    int g = blockIdx.x * 256 + threadIdx.x;
    int r = g / 6, c = g - r * 6;              // 6 chunks of 16 cols (96 features)
    if (r >= n) return;
    int4 cc = ((const int4*)xcat)[r];
    float v[16];
    int base = c * 16;
    #pragma unroll
    for (int j = 0; j < 16; ++j) {
        int col = base + j;
        float val;
        if      (col < 32) val = xnum[(size_t)r * 32 + col];
        else if (col < 42) val = e0[(size_t)cc.x * 10 + (col - 32)];
        else if (col < 48) val = e1[(size_t)cc.y * 6  + (col - 42)];
        else if (col < 53) val = e2[(size_t)cc.z * 5  + (col - 48)];
        else if (col < 71) val = e3[(size_t)cc.w * 18 + (col - 53)];
        else               val = 0.f;
        v[j] = val;
    }
    unsigned int ph[8];
    #pragma unroll
    for (int j = 0; j < 8; ++j)
        ph[j] = (unsigned int)f2bf(v[2*j]) | ((unsigned int)f2bf(v[2*j+1]) << 16);
    unsigned int* dh = (unsigned int*)(A0 + (size_t)r * 96 + base);
    uint4 a; a.x = ph[0]; a.y = ph[1]; a.z = ph[2]; a.w = ph[3];
    uint4 b; b.x = ph[4]; b.y = ph[5]; b.z = ph[6]; b.w = ph[7];
    ((uint4*)dh)[0] = a; ((uint4*)dh)[1] = b;
}

// ---------------- CSR build: rank (atomics paid once) + scan + atomic-free place ----------------
__global__ __launch_bounds__(256) void k_rank(const int* __restrict__ dst,
    int* __restrict__ cnt, int* __restrict__ rank, int ecount)
{
    int i = blockIdx.x * blockDim.x + threadIdx.x;
    int stride = gridDim.x * blockDim.x;
    for (; i < ecount; i += stride)
        rank[i] = atomicAdd(&cnt[dst[i]], 1);
}

__global__ __launch_bounds__(1024) void k_scan1(const int* __restrict__ cnt,
    int* __restrict__ excl, int* __restrict__ bsum, int n)
{
    __shared__ int sm[1024];
    int t = threadIdx.x;
    int base = blockIdx.x * 4096 + t * 4;
    int v0 = (base + 0 < n) ? cnt[base + 0] : 0;
    int v1 = (base + 1 < n) ? cnt[base + 1] : 0;
    int v2 = (base + 2 < n) ? cnt[base + 2] : 0;
    int v3 = (base + 3 < n) ? cnt[base + 3] : 0;
    int s = v0 + v1 + v2 + v3;
    sm[t] = s;
    __syncthreads();
    for (int offd = 1; offd < 1024; offd <<= 1) {
        int tv = (t >= offd) ? sm[t - offd] : 0;
        __syncthreads();
        sm[t] += tv;
        __syncthreads();
    }
    int incl = sm[t];
    int ex = incl - s;
    if (t == 1023) bsum[blockIdx.x] = incl;
    if (base + 0 < n) excl[base + 0] = ex; ex += v0;
    if (base + 1 < n) excl[base + 1] = ex; ex += v1;
    if (base + 2 < n) excl[base + 2] = ex; ex += v2;
    if (base + 3 < n) excl[base + 3] = ex;
}

__global__ void k_scan2(int* __restrict__ bsum, int nb)
{
    if (threadIdx.x == 0 && blockIdx.x == 0) {
        int run = 0;
        for (int i = 0; i < nb; ++i) { int t = bsum[i]; bsum[i] = run; run += t; }
    }
}

__global__ __launch_bounds__(256) void k_scan3(int* __restrict__ row_ptr,
    const int* __restrict__ bsum, int n, int ecount)
{
    int i = blockIdx.x * 256 + threadIdx.x;
    if (i < n)
        row_ptr[i] = row_ptr[i] + bsum[i >> 12];
    if (i == 0) row_ptr[n] = ecount;
}

// node-range-grouped placement: group g = blockIdx&7 handles nodes [g*per8,(g+1)*per8)
// -> each group's col region (~E/8*4B ~ 800 KB) stays L2-resident, written back once.
__global__ __launch_bounds__(256) void k_place(const int* __restrict__ src,
    const int* __restrict__ dst, const int* __restrict__ rank,
    const int* __restrict__ row_ptr, int* __restrict__ col, int ecount, int n)
{
    int g  = blockIdx.x & 7;
    int per8 = (n + 7) >> 3;
    int lo = g * per8;
    int hi = lo + per8 < n ? lo + per8 : n;
    int bl = blockIdx.x >> 3;
    int nb = gridDim.x >> 3;
    int i = bl * blockDim.x + threadIdx.x;
    int stride = nb * blockDim.x;
    for (; i < ecount; i += stride) {
        int d = dst[i];
        if (d >= lo && d < hi)
            col[row_ptr[d] + rank[i]] = src[i];
    }
}

// ---------------- mean aggregation (bf16): one wave per node, 2 edges/wave, unroll 4 ----------------
// lanes 0-31 = even edges, lanes 32-63 = odd edges; each lane covers 4 cols (uint2 = 8 B).
__global__ __launch_bounds__(256) void k_agg(
    const unsigned short* __restrict__ xh, unsigned short* __restrict__ mh, int SK,
    const int* __restrict__ row_ptr, const int* __restrict__ col, int n)
{
    int lane = threadIdx.x & 63;
    int half = lane >> 5;
    int l32  = lane & 31;
    int node = blockIdx.x * 4 + (threadIdx.x >> 6);
    if (node >= n) return;
    node = __builtin_amdgcn_readfirstlane(node);
    int s = row_ptr[node], e = row_ptr[node + 1];
    int deg = e - s;
    float a0 = 0.f, a1 = 0.f, a2 = 0.f, a3 = 0.f;
    size_t cOff = (size_t)l32 * 4;        // 4 bf16 cols per lane

    auto accum = [&](uint2 r) {
        a0 += __builtin_bit_cast(float, r.x << 16);
        a1 += __builtin_bit_cast(float, r.x & 0xffff0000u);
        a2 += __builtin_bit_cast(float, r.y << 16);
        a3 += __builtin_bit_cast(float, r.y & 0xffff0000u);
    };

    int p = s + half;
    for (; p + 6 < e; p += 8) {           // 4 pair-steps: edges p, p+2, p+4, p+6 (this half)
        int sc0 = col[p];
        int sc1 = col[p + 2];
        int sc2 = col[p + 4];
        int sc3 = col[p + 6];
        uint2 r0 = *(const uint2*)(xh + (size_t)sc0 * SK + cOff);
        uint2 r1 = *(const uint2*)(xh + (size_t)sc1 * SK + cOff);
        uint2 r2 = *(const uint2*)(xh + (size_t)sc2 * SK + cOff);
        uint2 r3 = *(const uint2*)(xh + (size_t)sc3 * SK + cOff);
        accum(r0); accum(r1); accum(r2); accum(r3);
    }
    for (; p < e; p += 2) {
        int sc = col[p];
        accum(*(const uint2*)(xh + (size_t)sc * SK + cOff));
    }

    a0 += __shfl_xor(a0, 32);
    a1 += __shfl_xor(a1, 32);
    a2 += __shfl_xor(a2, 32);
    a3 += __shfl_xor(a3, 32);

    if (half == 0) {
        float inv = 1.f / (float)(deg > 1 ? deg : 1);
        a0 *= inv; a1 *= inv; a2 *= inv; a3 *= inv;
        uint2 o;
        o.x = (unsigned int)f2bf(a0) | ((unsigned int)f2bf(a1) << 16);
        o.y = (unsigned int)f2bf(a2) | ((unsigned int)f2bf(a3) << 16);
        *(uint2*)(mh + (size_t)node * SK + cOff) = o;
    }
}

// ---------------- split-weight bf16-activation MFMA GEMM, M-tile=64, block=256 ----------------
// A row-major bf16 [m][SK], SK = KT8*32.  Weights split hi/lo.
// K-loop (#pragma unroll 1): per k-tile load ah,bh,bl once; groups Ah·Wh, Ah·Wl.
// Epilogue in 2 phases of 32 rows (LDS 16.9 KB), 8 threads/row.
// EPI 0: out = relu(C+bias) -> bf16 store.  EPI 1: LN+relu, out = res + 0.5*r -> bf16 store.
// EPI 2: head: s = relu(C+bias)·wh2 + bh2 -> outp.
template<int NC, int KT8, int EPI>
__global__ __launch_bounds__(256) void k_gemm(
    const unsigned short* __restrict__ A, int SK,
    const unsigned short* __restrict__ Whi, const unsigned short* __restrict__ Wlo,
    const float* __restrict__ bias,
    const float* __restrict__ g, const float* __restrict__ be,
    const unsigned short* __restrict__ Src, int SSK,
    unsigned short* __restrict__ Dst, int DSK,
    const float* __restrict__ wh2, const float* __restrict__ bh2, float* __restrict__ outp,
    int n)
{
    constexpr int NT = NC / 64;       // n-16-tiles per wave
    __shared__ float Cb[32][NC + 4];
    int t = threadIdx.x;
    int lane = t & 63, w = t >> 6;
    int l15 = lane & 15, kg = lane >> 4;
    int m0 = blockIdx.x * 64;

    size_t aoff[4];
    #pragma unroll
    for (int mt = 0; mt < 4; ++mt) {
        int r = m0 + mt * 16 + l15;
        r = r < n ? r : n - 1;
        aoff[mt] = (size_t)r * SK + kg * 8;
    }
    size_t nb[NT];
    #pragma unroll
    for (int nt = 0; nt < NT; ++nt)
        nb[nt] = (size_t)(w * (NC / 4) + nt * 16 + l15) * 32 + kg * 8;

    f32x4 acc[4][NT];
    #pragma unroll
    for (int mt = 0; mt < 4; ++mt)
        #pragma unroll
        for (int nt = 0; nt < NT; ++nt)
            acc[mt][nt] = (f32x4)(0.f);

    #pragma unroll 1
    for (int s = 0; s < KT8; ++s) {
        int koff = s * 32;
        short8 ah[4];
        #pragma unroll
        for (int mt = 0; mt < 4; ++mt)
            ah[mt] = *(const short8*)(A + aoff[mt] + koff);
        short8 bh[NT], bl[NT];
        #pragma unroll
        for (int nt = 0; nt < NT; ++nt) {
            bh[nt] = *(const short8*)(Whi + (size_t)s * NC * 32 + nb[nt]);
            bl[nt] = *(const short8*)(Wlo + (size_t)s * NC * 32 + nb[nt]);
        }
        #pragma unroll
        for (int mt = 0; mt < 4; ++mt)
            #pragma unroll
            for (int nt = 0; nt < NT; ++nt)
                acc[mt][nt] = __builtin_amdgcn_mfma_f32_16x16x32_bf16(ah[mt], bh[nt], acc[mt][nt], 0, 0, 0);
        #pragma unroll
        for (int mt = 0; mt < 4; ++mt)
            #pragma unroll
            for (int nt = 0; nt < NT; ++nt)
                acc[mt][nt] = __builtin_amdgcn_mfma_f32_16x16x32_bf16(ah[mt], bl[nt], acc[mt][nt], 0, 0, 0);
    }

    // Epilogue: two phases of 32 rows.  C/D layout: col = lane&15, row = quad*4 + reg.
    constexpr int CW = NC / 8;        // cols per epilogue thread (8 threads/row)
    int er = t >> 3, q = t & 7;
    int cb = q * CW;

    #pragma unroll
    for (int p = 0; p < 2; ++p) {
        if (p) __syncthreads();       // phase-0 readers done before overwrite
        #pragma unroll
        for (int mt2 = 0; mt2 < 2; ++mt2) {
            int mt = 2 * p + mt2;
            #pragma unroll
            for (int nt = 0; nt < NT; ++nt)
                #pragma unroll
                for (int r = 0; r < 4; ++r)
                    Cb[mt2 * 16 + kg * 4 + r][w * (NC / 4) + nt * 16 + l15] = acc[mt][nt][r];
        }
        __syncthreads();

        int gr = m0 + p * 32 + er;

        if (EPI == 0) {
            if (gr < n) {
                #pragma unroll
                for (int i = 0; i < CW / 4; ++i) {
                    int c = cb + 4 * i;
                    float4 v  = *(const float4*)&Cb[er][c];
                    float4 bi = *(const float4*)&bias[c];
                    ushort4 hv = make_ushort4(f2bf(fmaxf(v.x + bi.x, 0.f)),
                                              f2bf(fmaxf(v.y + bi.y, 0.f)),
                                              f2bf(fmaxf(v.z + bi.z, 0.f)),
                                              f2bf(fmaxf(v.w + bi.w, 0.f)));
                    *(ushort4*)(Dst + (size_t)gr * DSK + c) = hv;
                }
            }
        } else if (EPI == 1) {
            float s = 0.f, ss = 0.f;
            #pragma unroll
            for (int i = 0; i < CW / 4; ++i) {
                int c = cb + 4 * i;
                float4 v  = *(const float4*)&Cb[er][c];
                float4 bi = *(const float4*)&bias[c];
                float a0 = v.x + bi.x, a1 = v.y + bi.y, a2 = v.z + bi.z, a3 = v.w + bi.w;
                s  += a0 + a1 + a2 + a3;
                ss += a0 * a0 + a1 * a1 + a2 * a2 + a3 * a3;
            }
            s  += __shfl_xor(s, 1);  s  += __shfl_xor(s, 2);  s  += __shfl_xor(s, 4);
            ss += __shfl_xor(ss, 1); ss += __shfl_xor(ss, 2); ss += __shfl_xor(ss, 4);
            float mu  = s * (1.f / NC);
            float var = ss * (1.f / NC) - mu * mu;
            float rs  = rsqrtf(var + 1e-5f);
            if (gr < n) {
                #pragma unroll
                for (int i = 0; i < CW / 4; ++i) {
                    int c = cb + 4 * i;
                    float4 v  = *(const float4*)&Cb[er][c];
                    float4 bi = *(const float4*)&bias[c];
                    float4 gg = *(const float4*)&g[c];
                    float4 bb = *(const float4*)&be[c];
                    float r0 = fmaxf((v.x + bi.x - mu) * rs * gg.x + bb.x, 0.f);
                    float r1 = fmaxf((v.y + bi.y - mu) * rs * gg.y + bb.y, 0.f);
                    float r2 = fmaxf((v.z + bi.z - mu) * rs * gg.z + bb.z, 0.f);
                    float r3 = fmaxf((v.w + bi.w - mu) * rs * gg.w + bb.w, 0.f);
                    ushort4 rh = *(const ushort4*)(Src + (size_t)gr * SSK + c);
                    ushort4 hv = make_ushort4(f2bf(bf2f(rh.x) + 0.5f * r0),
                                              f2bf(bf2f(rh.y) + 0.5f * r1),
                                              f2bf(bf2f(rh.z) + 0.5f * r2),
                                              f2bf(bf2f(rh.w) + 0.5f * r3));
                    *(ushort4*)(Dst + (size_t)gr * DSK + c) = hv;
                }
            }
        } else {
            float s = 0.f;
            #pragma unroll
            for (int i = 0; i < CW / 4; ++i) {
                int c = cb + 4 * i;
                float4 v  = *(const float4*)&Cb[er][c];
                float4 bi = *(const float4*)&bias[c];
                float4 w2 = *(const float4*)&wh2[c];
                s += fmaxf(v.x + bi.x, 0.f) * w2.x + fmaxf(v.y + bi.y, 0.f) * w2.y
                   + fmaxf(v.z + bi.z, 0.f) * w2.z + fmaxf(v.w + bi.w, 0.f) * w2.w;
            }
            s += __shfl_xor(s, 1); s += __shfl_xor(s, 2); s += __shfl_xor(s, 4);
            if (q == 0 && gr < n) outp[gr] = s + bh2[0];
        }
    }
}

// ---------------- launcher ----------------
extern "C" void kernel_launch(void* const* d_in, const int* in_sizes, int n_in,
                              void* d_out, int out_size, void* d_ws, size_t ws_size,
                              hipStream_t stream)
{
    const float* xnum = (const float*)d_in[0];
    const int*   xcat = (const int*)d_in[1];
    const int*   eidx = (const int*)d_in[2];
    const float* e0   = (const float*)d_in[3];
    const float* e1   = (const float*)d_in[4];
    const float* e2   = (const float*)d_in[5];
    const float* e3   = (const float*)d_in[6];
    const float* w_in = (const float*)d_in[7];
    const float* b_in = (const float*)d_in[8];
    const float* w1l  = (const float*)d_in[9];
    const float* b1l  = (const float*)d_in[10];
    const float* w1r  = (const float*)d_in[11];
    const float* w2l  = (const float*)d_in[12];
    const float* b2l  = (const float*)d_in[13];
    const float* w2r  = (const float*)d_in[14];
    const float* g1   = (const float*)d_in[15];
    const float* be1  = (const float*)d_in[16];
    const float* g2   = (const float*)d_in[17];
    const float* be2  = (const float*)d_in[18];
    const float* wh1  = (const float*)d_in[19];
    const float* bh1  = (const float*)d_in[20];
    const float* wh2  = (const float*)d_in[21];
    const float* bh2  = (const float*)d_in[22];

    int n = in_sizes[0] / 32;
    int ecount = in_sizes[2] / 2;
    const int* esrc = eidx;
    const int* edst = eidx + ecount;

    char* ws = (char*)d_ws;
    size_t off = 0;
    auto alloc = [&](size_t bytes) -> void* {
        void* p = ws + off;
        off += (bytes + 255) & ~(size_t)255;
        return p;
    };
    // A1: n x 256 bf16 = [mean1(128) | x0(128)].  A3 (n x 128, x2) aliases it (A1 dead after conv1 GEMM).
    unsigned short* A1 = (unsigned short*)alloc((size_t)n * 256 * 2);
    unsigned short* A3 = A1;
    // A2: n x 256 = [mean2 | x1].  A0 (n x 96) aliases it (A0 dead before conv1 epilogue writes A2).
    unsigned short* A2 = (unsigned short*)alloc((size_t)n * 256 * 2);
    unsigned short* A0 = A2;
    // Weight fragment buffers (hi/lo split)
    unsigned short* w0h = (unsigned short*)alloc((size_t)96 * 128 * 2);
    unsigned short* w0l = (unsigned short*)alloc((size_t)96 * 128 * 2);
    unsigned short* w1h = (unsigned short*)alloc((size_t)256 * 128 * 2);
    unsigned short* w1lo= (unsigned short*)alloc((size_t)256 * 128 * 2);
    unsigned short* w2h = (unsigned short*)alloc((size_t)256 * 128 * 2);
    unsigned short* w2lo= (unsigned short*)alloc((size_t)256 * 128 * 2);
    unsigned short* whh = (unsigned short*)alloc((size_t)128 * 64 * 2);
    unsigned short* whl = (unsigned short*)alloc((size_t)128 * 64 * 2);
    // CSR
    int* cnt     = (int*)alloc((size_t)n * 4);
    int* row_ptr = (int*)alloc((size_t)(n + 1) * 4);
    int* rank    = (int*)alloc((size_t)ecount * 4);
    int* col     = (int*)alloc((size_t)ecount * 4);
    int nb1 = (n + 4095) / 4096;
    int* bsum    = (int*)alloc((size_t)nb1 * 4);
    (void)ws_size; (void)n_in; (void)out_size;

    int gemmBlocks = (n + 63) / 64;
    int gridE = 2048;
    int aggBlocks = (n + 3) / 4;

    // weight prep
    k_prepw<<<(96 * 128 + 255) / 256, 256, 0, stream>>>(w_in, 71, nullptr, 0, 96, 128, w0h, w0l);
    k_prepw<<<(256 * 128 + 255) / 256, 256, 0, stream>>>(w1l, 128, w1r, 128, 256, 128, w1h, w1lo);
    k_prepw<<<(256 * 128 + 255) / 256, 256, 0, stream>>>(w2l, 128, w2r, 128, 256, 128, w2h, w2lo);
    k_prepw<<<(128 * 64 + 255) / 256, 256, 0, stream>>>(wh1, 128, nullptr, 0, 128, 64, whh, whl);

    // input features -> A0 (bf16, 96 cols)
    k_stack0<<<((size_t)n * 6 + 255) / 256, 256, 0, stream>>>(xnum, xcat, e0, e1, e2, e3, A0, n);

    // CSR build (by dst): rank -> scan -> place
    hipMemsetAsync(cnt, 0, (size_t)n * 4, stream);
    k_rank<<<gridE, 256, 0, stream>>>(edst, cnt, rank, ecount);
    k_scan1<<<nb1, 1024, 0, stream>>>(cnt, row_ptr, bsum, n);
    k_scan2<<<1, 64, 0, stream>>>(bsum, nb1);
    k_scan3<<<(n + 255) / 256, 256, 0, stream>>>(row_ptr, bsum, n, ecount);
    k_place<<<gridE, 256, 0, stream>>>(esrc, edst, rank, row_ptr, col, ecount, n);

    // input MLP: A0[96] @ W0 -> x0 bf16 -> A1 x-slot (cols 128..255)
    k_gemm<128, 3, 0><<<gemmBlocks, 256, 0, stream>>>(
        A0, 96, w0h, w0l, b_in,
        nullptr, nullptr, nullptr, 0,
        A1 + 128, 256,
        nullptr, nullptr, nullptr, n);

    // conv1: mean of x0 -> A1 cols 0..127; GEMM A1[256] @ [w1l;w1r] -> x1 -> A2 x-slot
    k_agg<<<aggBlocks, 256, 0, stream>>>(A1 + 128, A1, 256, row_ptr, col, n);
    k_gemm<128, 8, 1><<<gemmBlocks, 256, 0, stream>>>(
        A1, 256, w1h, w1lo, b1l,
        g1, be1, A1 + 128, 256,
        A2 + 128, 256,
        nullptr, nullptr, nullptr, n);

    // conv2: mean of x1 -> A2 cols 0..127; GEMM A2[256] -> x2 -> A3 (128 cols/row)
    k_agg<<<aggBlocks, 256, 0, stream>>>(A2 + 128, A2, 256, row_ptr, col, n);
    k_gemm<128, 8, 1><<<gemmBlocks, 256, 0, stream>>>(
        A2, 256, w2h, w2lo, b2l,
        g2, be2, A2 + 128, 256,
        A3, 128,
        nullptr, nullptr, nullptr, n);

    // head: A3[128] @ wh1 -> relu -> ·wh2 + bh2 -> out
    k_gemm<64, 4, 2><<<gemmBlocks, 256, 0, stream>>>(
        A3, 128, whh, whl, bh1,
        nullptr, nullptr, nullptr, 0,
        nullptr, 0,
        wh2, bh2, (float*)d_out, n);
}

// Round 10
// 450.771 us; speedup vs baseline: 2.2037x; 1.1363x over previous
//
#include <hip/hip_runtime.h>

#define HID 128

typedef __attribute__((ext_vector_type(8))) short short8;
typedef __attribute__((ext_vector_type(4))) float f32x4;

__device__ __forceinline__ float bf2f(unsigned short u) {
    unsigned int x = ((unsigned int)u) << 16;
    return __builtin_bit_cast(float, x);
}
__device__ __forceinline__ unsigned short f2bf(float f) {
    unsigned int u = __builtin_bit_cast(unsigned int, f);
    u += 0x7fffu + ((u >> 16) & 1u);
    return (unsigned short)(u >> 16);
}

// ---------------- weight prep: fp32 [K,N] (optionally two stacked sources) ->
// fragment layout hi/lo: elem (k,n) at ((k/32)*N + n)*32 + k%32 ----------------
__global__ __launch_bounds__(256) void k_prepw(const float* __restrict__ s1, int k1,
    const float* __restrict__ s2, int k2, int Kp, int N,
    unsigned short* __restrict__ whi, unsigned short* __restrict__ wlo)
{
    int i = blockIdx.x * 256 + threadIdx.x;
    if (i >= Kp * N) return;
    int k = i / N, nn = i - k * N;
    float v = 0.f;
    if (k < k1) v = s1[(size_t)k * N + nn];
    else if (k < k1 + k2) v = s2[(size_t)(k - k1) * N + nn];
    unsigned short h = f2bf(v);
    unsigned short l = f2bf(v - bf2f(h));
    size_t o = ((size_t)(k >> 5) * N + nn) * 32 + (k & 31);
    whi[o] = h; wlo[o] = l;
}

// ---------------- input feature prestack: [xnum | emb0..3 | pad] -> bf16,
// A0 row-major [n][96].  6 chunks of 16 cols per row. ----------------
__global__ __launch_bounds__(256) void k_stack0(
    const float* __restrict__ xnum, const int* __restrict__ xcat,
    const float* __restrict__ e0, const float* __restrict__ e1,
    const float* __restrict__ e2, const float* __restrict__ e3,
    unsigned short* __restrict__ A0, int n)
{
    int g = blockIdx.x * 256 + threadIdx.x;
    int r = g / 6, c = g - r * 6;              // 6 chunks of 16 cols (96 features)
    if (r >= n) return;
    int4 cc = ((const int4*)xcat)[r];
    float v[16];
    int base = c * 16;
    #pragma unroll
    for (int j = 0; j < 16; ++j) {
        int col = base + j;
        float val;
        if      (col < 32) val = xnum[(size_t)r * 32 + col];
        else if (col < 42) val = e0[(size_t)cc.x * 10 + (col - 32)];
        else if (col < 48) val = e1[(size_t)cc.y * 6  + (col - 42)];
        else if (col < 53) val = e2[(size_t)cc.z * 5  + (col - 48)];
        else if (col < 71) val = e3[(size_t)cc.w * 18 + (col - 53)];
        else               val = 0.f;
        v[j] = val;
    }
    unsigned int ph[8];
    #pragma unroll
    for (int j = 0; j < 8; ++j)
        ph[j] = (unsigned int)f2bf(v[2*j]) | ((unsigned int)f2bf(v[2*j+1]) << 16);
    unsigned int* dh = (unsigned int*)(A0 + (size_t)r * 96 + base);
    uint4 a; a.x = ph[0]; a.y = ph[1]; a.z = ph[2]; a.w = ph[3];
    uint4 b; b.x = ph[4]; b.y = ph[5]; b.z = ph[6]; b.w = ph[7];
    ((uint4*)dh)[0] = a; ((uint4*)dh)[1] = b;
}

// ---------------- CSR build via bucketed counting sort (LDS atomics) ----------------
// Bucket = dst >> 8 (256 nodes/bucket).  k_part scatters edges into per-bucket
// regions; k_scanb scans bucket totals; k_bcsr builds row_ptr+col per bucket.
__global__ __launch_bounds__(256) void k_part(const int* __restrict__ esrc,
    const int* __restrict__ edst, int* __restrict__ gCur, int2* __restrict__ ebuf,
    int ecount, int chunk, int cap)
{
    __shared__ int hist[512];
    __shared__ int base[512];
    int t = threadIdx.x;
    hist[t] = 0; hist[t + 256] = 0;
    __syncthreads();
    int start = blockIdx.x * chunk;
    int end = start + chunk < ecount ? start + chunk : ecount;
    for (int i = start + t; i < end; i += 256)
        atomicAdd(&hist[edst[i] >> 8], 1);          // LDS
    __syncthreads();
    for (int bk = t; bk < 512; bk += 256) {
        int h = hist[bk];
        base[bk] = h ? atomicAdd(&gCur[bk], h) : 0; // global, 1 per (block,bucket)
        hist[bk] = 0;
    }
    __syncthreads();
    for (int i = start + t; i < end; i += 256) {
        int d = edst[i];
        int b = d >> 8;
        int slot = atomicAdd(&hist[b], 1);          // LDS
        int pos = base[b] + slot;
        if (pos < cap)
            ebuf[(size_t)b * cap + pos] = make_int2(esrc[i], d);
    }
}

__global__ __launch_bounds__(512) void k_scanb(const int* __restrict__ gCur,
    int* __restrict__ bBase, int* __restrict__ row_ptr, int nbuck, int n, int ecount)
{
    __shared__ int sm[512];
    int t = threadIdx.x;
    int c = (t < nbuck) ? gCur[t] : 0;
    sm[t] = c;
    __syncthreads();
    for (int d = 1; d < 512; d <<= 1) {
        int v = (t >= d) ? sm[t - d] : 0;
        __syncthreads();
        sm[t] += v;
        __syncthreads();
    }
    if (t < nbuck) bBase[t] = sm[t] - c;
    if (t == 0) row_ptr[n] = ecount;
}

__global__ __launch_bounds__(256) void k_bcsr(const int2* __restrict__ ebuf,
    const int* __restrict__ gCur, const int* __restrict__ bBase,
    int* __restrict__ row_ptr, int* __restrict__ col, int cap, int n)
{
    __shared__ int h[256];
    __shared__ int sm[256];
    int b = blockIdx.x, t = threadIdx.x;
    int cnt = gCur[b];
    int nb0 = b << 8;
    const int2* eb = ebuf + (size_t)b * cap;
    h[t] = 0;
    __syncthreads();
    for (int i = t; i < cnt; i += 256)
        atomicAdd(&h[eb[i].y & 255], 1);            // LDS histogram
    __syncthreads();
    int hv = h[t];
    sm[t] = hv;
    __syncthreads();
    for (int d = 1; d < 256; d <<= 1) {
        int v = (t >= d) ? sm[t - d] : 0;
        __syncthreads();
        sm[t] += v;
        __syncthreads();
    }
    int excl = sm[t] - hv;
    int gb = bBase[b];
    int g = nb0 + t;
    if (g < n) row_ptr[g] = gb + excl;
    __syncthreads();
    h[t] = excl;                                    // reuse as cursor
    __syncthreads();
    for (int i = t; i < cnt; i += 256) {
        int2 e = eb[i];
        int slot = atomicAdd(&h[e.y & 255], 1);     // LDS
        col[gb + slot] = e.x;
    }
}

// ---------------- mean aggregation (bf16): quarter-wave per edge, unroll 4 ----------------
// 16 lanes x uint4 (16 B) cover a 256 B row; 4 edges/wave-step, 16 gathers in flight.
__global__ __launch_bounds__(256) void k_agg(
    const unsigned short* __restrict__ xh, unsigned short* __restrict__ mh, int SK,
    const int* __restrict__ row_ptr, const int* __restrict__ col, int n)
{
    int lane = threadIdx.x & 63;
    int qw  = lane >> 4;
    int l16 = lane & 15;
    int node = blockIdx.x * 4 + (threadIdx.x >> 6);
    if (node >= n) return;
    node = __builtin_amdgcn_readfirstlane(node);
    int s = row_ptr[node], e = row_ptr[node + 1];
    int deg = e - s;
    float a0 = 0.f, a1 = 0.f, a2 = 0.f, a3 = 0.f;
    float a4 = 0.f, a5 = 0.f, a6 = 0.f, a7 = 0.f;
    size_t cOff = (size_t)l16 * 8;        // 8 bf16 cols per lane

    auto accum = [&](uint4 r) {
        a0 += __builtin_bit_cast(float, r.x << 16);
        a1 += __builtin_bit_cast(float, r.x & 0xffff0000u);
        a2 += __builtin_bit_cast(float, r.y << 16);
        a3 += __builtin_bit_cast(float, r.y & 0xffff0000u);
        a4 += __builtin_bit_cast(float, r.z << 16);
        a5 += __builtin_bit_cast(float, r.z & 0xffff0000u);
        a6 += __builtin_bit_cast(float, r.w << 16);
        a7 += __builtin_bit_cast(float, r.w & 0xffff0000u);
    };

    int p = s + qw;
    for (; p + 12 < e; p += 16) {         // 4 steps: edges p, p+4, p+8, p+12 (this quarter)
        int sc0 = col[p];
        int sc1 = col[p + 4];
        int sc2 = col[p + 8];
        int sc3 = col[p + 12];
        uint4 r0 = *(const uint4*)(xh + (size_t)sc0 * SK + cOff);
        uint4 r1 = *(const uint4*)(xh + (size_t)sc1 * SK + cOff);
        uint4 r2 = *(const uint4*)(xh + (size_t)sc2 * SK + cOff);
        uint4 r3 = *(const uint4*)(xh + (size_t)sc3 * SK + cOff);
        accum(r0); accum(r1); accum(r2); accum(r3);
    }
    for (; p < e; p += 4) {
        int sc = col[p];
        accum(*(const uint4*)(xh + (size_t)sc * SK + cOff));
    }

    a0 += __shfl_xor(a0, 16); a0 += __shfl_xor(a0, 32);
    a1 += __shfl_xor(a1, 16); a1 += __shfl_xor(a1, 32);
    a2 += __shfl_xor(a2, 16); a2 += __shfl_xor(a2, 32);
    a3 += __shfl_xor(a3, 16); a3 += __shfl_xor(a3, 32);
    a4 += __shfl_xor(a4, 16); a4 += __shfl_xor(a4, 32);
    a5 += __shfl_xor(a5, 16); a5 += __shfl_xor(a5, 32);
    a6 += __shfl_xor(a6, 16); a6 += __shfl_xor(a6, 32);
    a7 += __shfl_xor(a7, 16); a7 += __shfl_xor(a7, 32);

    if (qw == 0) {
        float inv = 1.f / (float)(deg > 1 ? deg : 1);
        uint4 o;
        o.x = (unsigned int)f2bf(a0 * inv) | ((unsigned int)f2bf(a1 * inv) << 16);
        o.y = (unsigned int)f2bf(a2 * inv) | ((unsigned int)f2bf(a3 * inv) << 16);
        o.z = (unsigned int)f2bf(a4 * inv) | ((unsigned int)f2bf(a5 * inv) << 16);
        o.w = (unsigned int)f2bf(a6 * inv) | ((unsigned int)f2bf(a7 * inv) << 16);
        *(uint4*)(mh + (size_t)node * SK + cOff) = o;
    }
}

// ---------------- split-weight bf16-activation MFMA GEMM, M-tile=64, block=256 ----------------
// A row-major bf16 [m][SK], SK = KT8*32.  Weights split hi/lo.
// K-loop (#pragma unroll 1): per k-tile load ah,bh,bl once; groups Ah·Wh, Ah·Wl.
// Epilogue in 2 phases of 32 rows (LDS 16.9 KB), 8 threads/row.
// EPI 0: out = relu(C+bias) -> bf16 store.  EPI 1: LN+relu, out = res + 0.5*r -> bf16 store.
// EPI 2: head: s = relu(C+bias)·wh2 + bh2 -> outp.
template<int NC, int KT8, int EPI>
__global__ __launch_bounds__(256) void k_gemm(
    const unsigned short* __restrict__ A, int SK,
    const unsigned short* __restrict__ Whi, const unsigned short* __restrict__ Wlo,
    const float* __restrict__ bias,
    const float* __restrict__ g, const float* __restrict__ be,
    const unsigned short* __restrict__ Src, int SSK,
    unsigned short* __restrict__ Dst, int DSK,
    const float* __restrict__ wh2, const float* __restrict__ bh2, float* __restrict__ outp,
    int n)
{
    constexpr int NT = NC / 64;       // n-16-tiles per wave
    __shared__ float Cb[32][NC + 4];
    int t = threadIdx.x;
    int lane = t & 63, w = t >> 6;
    int l15 = lane & 15, kg = lane >> 4;
    int m0 = blockIdx.x * 64;

    size_t aoff[4];
    #pragma unroll
    for (int mt = 0; mt < 4; ++mt) {
        int r = m0 + mt * 16 + l15;
        r = r < n ? r : n - 1;
        aoff[mt] = (size_t)r * SK + kg * 8;
    }
    size_t nb[NT];
    #pragma unroll
    for (int nt = 0; nt < NT; ++nt)
        nb[nt] = (size_t)(w * (NC / 4) + nt * 16 + l15) * 32 + kg * 8;

    f32x4 acc[4][NT];
    #pragma unroll
    for (int mt = 0; mt < 4; ++mt)
        #pragma unroll
        for (int nt = 0; nt < NT; ++nt)
            acc[mt][nt] = (f32x4)(0.f);

    #pragma unroll 1
    for (int s = 0; s < KT8; ++s) {
        int koff = s * 32;
        short8 ah[4];
        #pragma unroll
        for (int mt = 0; mt < 4; ++mt)
            ah[mt] = *(const short8*)(A + aoff[mt] + koff);
        short8 bh[NT], bl[NT];
        #pragma unroll
        for (int nt = 0; nt < NT; ++nt) {
            bh[nt] = *(const short8*)(Whi + (size_t)s * NC * 32 + nb[nt]);
            bl[nt] = *(const short8*)(Wlo + (size_t)s * NC * 32 + nb[nt]);
        }
        #pragma unroll
        for (int mt = 0; mt < 4; ++mt)
            #pragma unroll
            for (int nt = 0; nt < NT; ++nt)
                acc[mt][nt] = __builtin_amdgcn_mfma_f32_16x16x32_bf16(ah[mt], bh[nt], acc[mt][nt], 0, 0, 0);
        #pragma unroll
        for (int mt = 0; mt < 4; ++mt)
            #pragma unroll
            for (int nt = 0; nt < NT; ++nt)
                acc[mt][nt] = __builtin_amdgcn_mfma_f32_16x16x32_bf16(ah[mt], bl[nt], acc[mt][nt], 0, 0, 0);
    }

    // Epilogue: two phases of 32 rows.  C/D layout: col = lane&15, row = quad*4 + reg.
    constexpr int CW = NC / 8;        // cols per epilogue thread (8 threads/row)
    int er = t >> 3, q = t & 7;
    int cb = q * CW;

    #pragma unroll
    for (int p = 0; p < 2; ++p) {
        if (p) __syncthreads();       // phase-0 readers done before overwrite
        #pragma unroll
        for (int mt2 = 0; mt2 < 2; ++mt2) {
            int mt = 2 * p + mt2;
            #pragma unroll
            for (int nt = 0; nt < NT; ++nt)
                #pragma unroll
                for (int r = 0; r < 4; ++r)
                    Cb[mt2 * 16 + kg * 4 + r][w * (NC / 4) + nt * 16 + l15] = acc[mt][nt][r];
        }
        __syncthreads();

        int gr = m0 + p * 32 + er;

        if (EPI == 0) {
            if (gr < n) {
                #pragma unroll
                for (int i = 0; i < CW / 4; ++i) {
                    int c = cb + 4 * i;
                    float4 v  = *(const float4*)&Cb[er][c];
                    float4 bi = *(const float4*)&bias[c];
                    ushort4 hv = make_ushort4(f2bf(fmaxf(v.x + bi.x, 0.f)),
                                              f2bf(fmaxf(v.y + bi.y, 0.f)),
                                              f2bf(fmaxf(v.z + bi.z, 0.f)),
                                              f2bf(fmaxf(v.w + bi.w, 0.f)));
                    *(ushort4*)(Dst + (size_t)gr * DSK + c) = hv;
                }
            }
        } else if (EPI == 1) {
            float s = 0.f, ss = 0.f;
            #pragma unroll
            for (int i = 0; i < CW / 4; ++i) {
                int c = cb + 4 * i;
                float4 v  = *(const float4*)&Cb[er][c];
                float4 bi = *(const float4*)&bias[c];
                float a0 = v.x + bi.x, a1 = v.y + bi.y, a2 = v.z + bi.z, a3 = v.w + bi.w;
                s  += a0 + a1 + a2 + a3;
                ss += a0 * a0 + a1 * a1 + a2 * a2 + a3 * a3;
            }
            s  += __shfl_xor(s, 1);  s  += __shfl_xor(s, 2);  s  += __shfl_xor(s, 4);
            ss += __shfl_xor(ss, 1); ss += __shfl_xor(ss, 2); ss += __shfl_xor(ss, 4);
            float mu  = s * (1.f / NC);
            float var = ss * (1.f / NC) - mu * mu;
            float rs  = rsqrtf(var + 1e-5f);
            if (gr < n) {
                #pragma unroll
                for (int i = 0; i < CW / 4; ++i) {
                    int c = cb + 4 * i;
                    float4 v  = *(const float4*)&Cb[er][c];
                    float4 bi = *(const float4*)&bias[c];
                    float4 gg = *(const float4*)&g[c];
                    float4 bb = *(const float4*)&be[c];
                    float r0 = fmaxf((v.x + bi.x - mu) * rs * gg.x + bb.x, 0.f);
                    float r1 = fmaxf((v.y + bi.y - mu) * rs * gg.y + bb.y, 0.f);
                    float r2 = fmaxf((v.z + bi.z - mu) * rs * gg.z + bb.z, 0.f);
                    float r3 = fmaxf((v.w + bi.w - mu) * rs * gg.w + bb.w, 0.f);
                    ushort4 rh = *(const ushort4*)(Src + (size_t)gr * SSK + c);
                    ushort4 hv = make_ushort4(f2bf(bf2f(rh.x) + 0.5f * r0),
                                              f2bf(bf2f(rh.y) + 0.5f * r1),
                                              f2bf(bf2f(rh.z) + 0.5f * r2),
                                              f2bf(bf2f(rh.w) + 0.5f * r3));
                    *(ushort4*)(Dst + (size_t)gr * DSK + c) = hv;
                }
            }
        } else {
            float s = 0.f;
            #pragma unroll
            for (int i = 0; i < CW / 4; ++i) {
                int c = cb + 4 * i;
                float4 v  = *(const float4*)&Cb[er][c];
                float4 bi = *(const float4*)&bias[c];
                float4 w2 = *(const float4*)&wh2[c];
                s += fmaxf(v.x + bi.x, 0.f) * w2.x + fmaxf(v.y + bi.y, 0.f) * w2.y
                   + fmaxf(v.z + bi.z, 0.f) * w2.z + fmaxf(v.w + bi.w, 0.f) * w2.w;
            }
            s += __shfl_xor(s, 1); s += __shfl_xor(s, 2); s += __shfl_xor(s, 4);
            if (q == 0 && gr < n) outp[gr] = s + bh2[0];
        }
    }
}

// ---------------- launcher ----------------
extern "C" void kernel_launch(void* const* d_in, const int* in_sizes, int n_in,
                              void* d_out, int out_size, void* d_ws, size_t ws_size,
                              hipStream_t stream)
{
    const float* xnum = (const float*)d_in[0];
    const int*   xcat = (const int*)d_in[1];
    const int*   eidx = (const int*)d_in[2];
    const float* e0   = (const float*)d_in[3];
    const float* e1   = (const float*)d_in[4];
    const float* e2   = (const float*)d_in[5];
    const float* e3   = (const float*)d_in[6];
    const float* w_in = (const float*)d_in[7];
    const float* b_in = (const float*)d_in[8];
    const float* w1l  = (const float*)d_in[9];
    const float* b1l  = (const float*)d_in[10];
    const float* w1r  = (const float*)d_in[11];
    const float* w2l  = (const float*)d_in[12];
    const float* b2l  = (const float*)d_in[13];
    const float* w2r  = (const float*)d_in[14];
    const float* g1   = (const float*)d_in[15];
    const float* be1  = (const float*)d_in[16];
    const float* g2   = (const float*)d_in[17];
    const float* be2  = (const float*)d_in[18];
    const float* wh1  = (const float*)d_in[19];
    const float* bh1  = (const float*)d_in[20];
    const float* wh2  = (const float*)d_in[21];
    const float* bh2  = (const float*)d_in[22];

    int n = in_sizes[0] / 32;
    int ecount = in_sizes[2] / 2;
    const int* esrc = eidx;
    const int* edst = eidx + ecount;

    char* ws = (char*)d_ws;
    size_t off = 0;
    auto alloc = [&](size_t bytes) -> void* {
        void* p = ws + off;
        off += (bytes + 255) & ~(size_t)255;
        return p;
    };
    // A1: n x 256 bf16 = [mean1(128) | x0(128)].  A3 (n x 128, x2) aliases it.
    unsigned short* A1 = (unsigned short*)alloc((size_t)n * 256 * 2);
    unsigned short* A3 = A1;
    // A2: n x 256 = [mean2 | x1].  A0 (n x 96) aliases it.
    unsigned short* A2 = (unsigned short*)alloc((size_t)n * 256 * 2);
    unsigned short* A0 = A2;
    // Weight fragment buffers (hi/lo split)
    unsigned short* w0h = (unsigned short*)alloc((size_t)96 * 128 * 2);
    unsigned short* w0l = (unsigned short*)alloc((size_t)96 * 128 * 2);
    unsigned short* w1h = (unsigned short*)alloc((size_t)256 * 128 * 2);
    unsigned short* w1lo= (unsigned short*)alloc((size_t)256 * 128 * 2);
    unsigned short* w2h = (unsigned short*)alloc((size_t)256 * 128 * 2);
    unsigned short* w2lo= (unsigned short*)alloc((size_t)256 * 128 * 2);
    unsigned short* whh = (unsigned short*)alloc((size_t)128 * 64 * 2);
    unsigned short* whl = (unsigned short*)alloc((size_t)128 * 64 * 2);
    // CSR via bucketed counting sort
    int nbuck = (n + 255) >> 8;
    int cap = ecount / nbuck + ecount / (2 * nbuck) + 256;   // mean + 50% + slack
    int* gCur    = (int*)alloc(512 * 4);
    int* bBase   = (int*)alloc(512 * 4);
    int* row_ptr = (int*)alloc((size_t)(n + 1) * 4);
    int* col     = (int*)alloc((size_t)ecount * 4);
    int2* ebuf   = (int2*)alloc((size_t)nbuck * cap * 8);
    (void)ws_size; (void)n_in; (void)out_size;

    int gemmBlocks = (n + 63) / 64;
    int aggBlocks = (n + 3) / 4;

    // weight prep
    k_prepw<<<(96 * 128 + 255) / 256, 256, 0, stream>>>(w_in, 71, nullptr, 0, 96, 128, w0h, w0l);
    k_prepw<<<(256 * 128 + 255) / 256, 256, 0, stream>>>(w1l, 128, w1r, 128, 256, 128, w1h, w1lo);
    k_prepw<<<(256 * 128 + 255) / 256, 256, 0, stream>>>(w2l, 128, w2r, 128, 256, 128, w2h, w2lo);
    k_prepw<<<(128 * 64 + 255) / 256, 256, 0, stream>>>(wh1, 128, nullptr, 0, 128, 64, whh, whl);

    // input features -> A0 (bf16, 96 cols)
    k_stack0<<<((size_t)n * 6 + 255) / 256, 256, 0, stream>>>(xnum, xcat, e0, e1, e2, e3, A0, n);

    // CSR build: partition -> bucket scan -> per-bucket CSR
    hipMemsetAsync(gCur, 0, 512 * 4, stream);
    int nblkP = 512;
    int chunk = (ecount + nblkP - 1) / nblkP;
    k_part<<<nblkP, 256, 0, stream>>>(esrc, edst, gCur, ebuf, ecount, chunk, cap);
    k_scanb<<<1, 512, 0, stream>>>(gCur, bBase, row_ptr, nbuck, n, ecount);
    k_bcsr<<<nbuck, 256, 0, stream>>>(ebuf, gCur, bBase, row_ptr, col, cap, n);

    // input MLP: A0[96] @ W0 -> x0 bf16 -> A1 x-slot (cols 128..255)
    k_gemm<128, 3, 0><<<gemmBlocks, 256, 0, stream>>>(
        A0, 96, w0h, w0l, b_in,
        nullptr, nullptr, nullptr, 0,
        A1 + 128, 256,
        nullptr, nullptr, nullptr, n);

    // conv1: mean of x0 -> A1 cols 0..127; GEMM A1[256] @ [w1l;w1r] -> x1 -> A2 x-slot
    k_agg<<<aggBlocks, 256, 0, stream>>>(A1 + 128, A1, 256, row_ptr, col, n);
    k_gemm<128, 8, 1><<<gemmBlocks, 256, 0, stream>>>(
        A1, 256, w1h, w1lo, b1l,
        g1, be1, A1 + 128, 256,
        A2 + 128, 256,
        nullptr, nullptr, nullptr, n);

    // conv2: mean of x1 -> A2 cols 0..127; GEMM A2[256] -> x2 -> A3 (128 cols/row)
    k_agg<<<aggBlocks, 256, 0, stream>>>(A2 + 128, A2, 256, row_ptr, col, n);
    k_gemm<128, 8, 1><<<gemmBlocks, 256, 0, stream>>>(
        A2, 256, w2h, w2lo, b2l,
        g2, be2, A2 + 128, 256,
        A3, 128,
        nullptr, nullptr, nullptr, n);

    // head: A3[128] @ wh1 -> relu -> ·wh2 + bh2 -> out
    k_gemm<64, 4, 2><<<gemmBlocks, 256, 0, stream>>>(
        A3, 128, whh, whl, bh1,
        nullptr, nullptr, nullptr, 0,
        nullptr, 0,
        wh2, bh2, (float*)d_out, n);
}